// Round 3
// baseline (1556.587 us; speedup 1.0000x reference)
//
#include <hip/hip_runtime.h>
#include <hip/hip_bf16.h>
#include <cstdint>
#include <cstddef>

#define T_SEQ 2048
#define CDIM  2048
#define HQ    16
#define HKV   4
#define DHEAD 128
#define NQKV  3072   // q(2048) | k(512) | v(512)

typedef __bf16 bf8 __attribute__((ext_vector_type(8)));
typedef __bf16 bf4 __attribute__((ext_vector_type(4)));
typedef float  f4  __attribute__((ext_vector_type(4)));

static __device__ __forceinline__ f4 mfma16(bf8 a, bf8 b, f4 c) {
    return __builtin_amdgcn_mfma_f32_16x16x32_bf16(a, b, c, 0, 0, 0);
}

#define GLOAD16(g, l)                                                        \
    __builtin_amdgcn_global_load_lds(                                        \
        (const __attribute__((address_space(1))) void*)(g),                  \
        (__attribute__((address_space(3))) void*)(l), 16, 0, 0)

static __device__ __forceinline__ float toF(float v) { return v; }
static __device__ __forceinline__ float toF(__bf16 v) { return (float)v; }

// ---------------- fp32 -> bf16 elementwise (x) ----------------
__global__ __launch_bounds__(256) void k_cvt(const float* __restrict__ in,
                                             __bf16* __restrict__ out, int n4) {
    int i = blockIdx.x * 256 + threadIdx.x;
    if (i >= n4) return;
    float4 v = ((const float4*)in)[i];
    bf4 o;
    o[0] = (__bf16)v.x; o[1] = (__bf16)v.y; o[2] = (__bf16)v.z; o[3] = (__bf16)v.w;
    ((bf4*)out)[i] = o;
}

// ---------------- transpose + convert: dst[c][r] = src[r][c] ----------------
template <typename TS>
__global__ __launch_bounds__(256) void k_tpose(const TS* __restrict__ src, int ld_src,
                                               __bf16* __restrict__ dst, int ld_dst,
                                               int R, int C) {
    __shared__ float tile[32][33];
    const int c0 = blockIdx.x * 32, r0 = blockIdx.y * 32;
    const int tx = threadIdx.x, ty = threadIdx.y;
#pragma unroll
    for (int i = 0; i < 4; ++i)
        tile[ty + i * 8][tx] = toF(src[(size_t)(r0 + ty + i * 8) * ld_src + c0 + tx]);
    __syncthreads();
#pragma unroll
    for (int i = 0; i < 4; ++i)
        dst[(size_t)(c0 + ty + i * 8) * ld_dst + r0 + tx] = (__bf16)tile[tx][ty + i * 8];
}

// ---------------- RoPE cos/sin table [T][64][2] ----------------
__global__ __launch_bounds__(256) void k_rtab(float* __restrict__ tab) {
    int idx = blockIdx.x * 256 + threadIdx.x;  // T*64
    int t = idx >> 6, j = idx & 63;
    float invf = expf(-(float)j * (9.210340371976184f / 64.0f));  // 10000^(-j/64)
    float a = (float)t * invf;
    tab[idx * 2 + 0] = cosf(a);
    tab[idx * 2 + 1] = sinf(a);
}

// ---------------- RoPE apply: qkv(bf16) -> Q [H][T][D], K [HKV][T][D] ----------------
__global__ __launch_bounds__(256) void k_rope(const __bf16* __restrict__ qkv,
                                              const float* __restrict__ tab,
                                              __bf16* __restrict__ Q,
                                              __bf16* __restrict__ K) {
    int idx = blockIdx.x * 256 + threadIdx.x;  // T * 20 * 64
    int j = idx & 63;
    int hd = (idx >> 6) % 20;
    int t = idx / (20 * 64);
    const __bf16* base;
    __bf16* dst;
    if (hd < HQ) {
        base = qkv + (size_t)t * NQKV + hd * DHEAD;
        dst = Q + ((size_t)hd * T_SEQ + t) * DHEAD;
    } else {
        int kvh = hd - HQ;
        base = qkv + (size_t)t * NQKV + CDIM + kvh * DHEAD;
        dst = K + ((size_t)kvh * T_SEQ + t) * DHEAD;
    }
    float a = (float)base[j], b = (float)base[j + 64];
    float c = tab[(t * 64 + j) * 2 + 0];
    float s = tab[(t * 64 + j) * 2 + 1];
    dst[j] = (__bf16)(a * c - b * s);
    dst[j + 64] = (__bf16)(b * c + a * s);
}

// ---------------- GEMM (m97-style): C[M][N] = A[M][K] * BT[N][K]^T ----------------
// 128x128 tile, BK=32, global_load_lds(16B) staging, XOR-swizzled LDS
// (pre-swizzled global source, linear LDS dest; read applies same XOR).
template <bool OBF>
__global__ __launch_bounds__(256) void k_gemm_bt(const __bf16* __restrict__ A,
                                                 const __bf16* __restrict__ BT,
                                                 void* __restrict__ C,
                                                 int M, int N, int K, int ldc) {
    __shared__ __bf16 Al[128 * 32];  // linear, 64B rows
    __shared__ __bf16 Bl[128 * 32];
    const int tid = threadIdx.x;
    const int wid = tid >> 6, lane = tid & 63;
    const int l15 = lane & 15, lhi = lane >> 4;
    const int wr = wid >> 1, wc = wid & 1;
    const size_t arow0 = (size_t)blockIdx.y * 128;
    const size_t brow0 = (size_t)blockIdx.x * 128;

    // staging source addressing (inverse-swizzled): row = i*64 + wid*16 + lane/4,
    // col elems = ((lane&3) ^ ((lane>>3)&3)) * 8
    const int srow = wid * 16 + (lane >> 2);
    const int scol = ((lane & 3) ^ ((lane >> 3) & 3)) * 8;
    const __bf16* Ag0 = A + (arow0 + srow) * K + scol;
    const __bf16* Ag1 = Ag0 + (size_t)64 * K;
    const __bf16* Bg0 = BT + (brow0 + srow) * K + scol;
    const __bf16* Bg1 = Bg0 + (size_t)64 * K;
    char* AlB = (char*)&Al[0];
    char* BlB = (char*)&Bl[0];

    f4 acc[4][4] = {};
    // frag read swizzle: phys = r*64 + (lhi ^ ((r>>1)&3))*16 ; (r>>1)&3 == (l15>>1)&3
    const int c16 = (lhi ^ ((l15 >> 1) & 3)) * 16;

    for (int k0 = 0; k0 < K; k0 += 32) {
        GLOAD16(Ag0 + k0, AlB + wid * 1024);
        GLOAD16(Ag1 + k0, AlB + 4096 + wid * 1024);
        GLOAD16(Bg0 + k0, BlB + wid * 1024);
        GLOAD16(Bg1 + k0, BlB + 4096 + wid * 1024);
        __syncthreads();
        bf8 af[4], bfr[4];
#pragma unroll
        for (int m = 0; m < 4; ++m) {
            int r = wr * 64 + m * 16 + l15;
            af[m] = *(const bf8*)(AlB + r * 64 + c16);
        }
#pragma unroll
        for (int n = 0; n < 4; ++n) {
            int r = wc * 64 + n * 16 + l15;
            bfr[n] = *(const bf8*)(BlB + r * 64 + c16);
        }
#pragma unroll
        for (int m = 0; m < 4; ++m)
#pragma unroll
            for (int n = 0; n < 4; ++n)
                acc[m][n] = mfma16(af[m], bfr[n], acc[m][n]);
        __syncthreads();
    }

    const int row0 = blockIdx.y * 128 + wr * 64, col0 = blockIdx.x * 128 + wc * 64;
#pragma unroll
    for (int m = 0; m < 4; ++m)
#pragma unroll
        for (int n = 0; n < 4; ++n)
#pragma unroll
            for (int j = 0; j < 4; ++j) {
                int r = row0 + m * 16 + lhi * 4 + j;
                int c = col0 + n * 16 + l15;
                float v = acc[m][n][j];
                if (OBF)
                    ((__bf16*)C)[(size_t)r * ldc + c] = (__bf16)v;
                else
                    ((float*)C)[(size_t)r * ldc + c] = v;
            }
}

// ---------------- barrier-free dual-softmax flash attention ----------------
// 256 blocks x 512 threads (8 waves). Wave w handles 16 q-rows; processes
// q-tile blockIdx.x in one phase and 31-blockIdx.x in the other -> ~66 tiles
// per wave, uniform. K/V read direct from global (L2-resident). Shared-exp
// dual softmax with defer-max; per-lane partial sums reduced once at end.
__global__ __launch_bounds__(512) void k_attn(const __bf16* __restrict__ Q,
                                              const __bf16* __restrict__ Kr,
                                              const __bf16* __restrict__ VT,
                                              __bf16* __restrict__ att) {
    __shared__ __bf16 Pg[8][16][40];   // per-wave P transpose (global branch)
    __shared__ __bf16 Pw[8][16][40];   // per-wave P transpose (local partial)
    const int h = blockIdx.y, kvh = h >> 2;
    const int tid = threadIdx.x, wid = tid >> 6, lane = tid & 63;
    const int l15 = lane & 15, lhi = lane >> 4;
    const int w4 = wid & 3;
    const float scale = 0.08838834764831845f;  // 1/sqrt(128)
    const float L2E = 1.44269504088896340736f;
    const float THR = 5.545177444479562f;      // 8*ln2 -> p <= 256

    for (int ph = 0; ph < 2; ++ph) {
        const int qsel = (wid < 4) ? ph : (1 - ph);
        const int qt = qsel ? (31 - (int)blockIdx.x) : (int)blockIdx.x;
        const int q0w = qt * 64 + w4 * 16;
        const int iblk = (qt >> 2) << 8;
        const int kst = iblk >= 128 ? iblk - 128 : 0;
        const int off = iblk - kst;
        const int ntw = (q0w + 47) >> 5;  // tiles covering keys <= q0w+15

        bf8 qf[4];
#pragma unroll
        for (int dc = 0; dc < 4; ++dc)
            qf[dc] = *(const bf8*)&Q[((size_t)h * T_SEQ + q0w + l15) * DHEAD + dc * 32 + lhi * 8];

        f4 og[8] = {}, ol[8] = {};
        float mg[4], sgp[4], slp[4];
#pragma unroll
        for (int j = 0; j < 4; ++j) { mg[j] = -__builtin_inff(); sgp[j] = slp[j] = 0.f; }

        for (int kt = 0; kt < ntw; ++kt) {
            const int kb = kt * 32;
            // ---- QK^T: K direct from global ----
            f4 sc0 = {}, sc1 = {};
#pragma unroll
            for (int dc = 0; dc < 4; ++dc) {
                bf8 kf = *(const bf8*)&Kr[((size_t)kvh * T_SEQ + kb + l15) * DHEAD + dc * 32 + lhi * 8];
                sc0 = mfma16(qf[dc], kf, sc0);
            }
#pragma unroll
            for (int dc = 0; dc < 4; ++dc) {
                bf8 kf = *(const bf8*)&Kr[((size_t)kvh * T_SEQ + kb + 16 + l15) * DHEAD + dc * 32 + lhi * 8];
                sc1 = mfma16(qf[dc], kf, sc1);
            }
            const bool interior = (kb + 31 <= q0w);
            float p0[4], p1[4];
#pragma unroll
            for (int j = 0; j < 4; ++j) {
                const int q = q0w + lhi * 4 + j;
                float s0 = sc0[j] * scale, s1 = sc1[j] * scale;
                if (!interior) {
                    if (kb + l15 > q) s0 = -3.0e38f;
                    if (kb + 16 + l15 > q) s1 = -3.0e38f;
                }
                float mx = fmaxf(s0, s1);
                if (!__all(mx <= mg[j] + THR)) {
                    float m2 = mx;
#pragma unroll
                    for (int x = 1; x < 16; x <<= 1) m2 = fmaxf(m2, __shfl_xor(m2, x));
                    float mn = fmaxf(mg[j], m2);
                    float f = exp2f((fmaxf(mg[j], -1.0e30f) - fmaxf(mn, -1.0e30f)) * L2E);
                    mg[j] = mn;
                    sgp[j] *= f; slp[j] *= f;
#pragma unroll
                    for (int nd = 0; nd < 8; ++nd) { og[nd][j] *= f; ol[nd][j] *= f; }
                }
                const float mref = fmaxf(mg[j], -1.0e30f);
                p0[j] = exp2f((s0 - mref) * L2E);
                p1[j] = exp2f((s1 - mref) * L2E);
                sgp[j] += p0[j] + p1[j];
            }
            // ---- P transpose (global) ----
#pragma unroll
            for (int j = 0; j < 4; ++j) {
                Pg[wid][lhi * 4 + j][l15] = (__bf16)p0[j];
                Pg[wid][lhi * 4 + j][16 + l15] = (__bf16)p1[j];
            }
            bf8 pf = *(const bf8*)&Pg[wid][l15][lhi * 8];
            // ---- local branch bookkeeping ----
            const bool lact = (kb <= q0w + 15 - off) && (kb + 31 >= kst);
            const bool lfull = lact && (kb >= kst) && (kb + 31 <= q0w - off);
            bf8 pfl = pf;
            if (lact) {
                if (lfull) {
#pragma unroll
                    for (int j = 0; j < 4; ++j) slp[j] += p0[j] + p1[j];
                } else {
#pragma unroll
                    for (int j = 0; j < 4; ++j) {
                        const int q = q0w + lhi * 4 + j;
                        const int up = q - off;
                        int kc0 = kb + l15, kc1 = kb + 16 + l15;
                        float l0 = (kc0 >= kst && kc0 <= up) ? p0[j] : 0.f;
                        float l1 = (kc1 >= kst && kc1 <= up) ? p1[j] : 0.f;
                        slp[j] += l0 + l1;
                        Pw[wid][lhi * 4 + j][l15] = (__bf16)l0;
                        Pw[wid][lhi * 4 + j][16 + l15] = (__bf16)l1;
                    }
                    pfl = *(const bf8*)&Pw[wid][l15][lhi * 8];
                }
            }
            // ---- PV: V direct from global (shared between branches) ----
#pragma unroll
            for (int nd = 0; nd < 8; ++nd) {
                bf8 vf = *(const bf8*)&VT[((size_t)kvh * DHEAD + nd * 16 + l15) * T_SEQ + kb + lhi * 8];
                og[nd] = mfma16(pf, vf, og[nd]);
                if (lact) ol[nd] = mfma16(pfl, vf, ol[nd]);
            }
        }

        // ---- single final reduction of denominators across the 16-lane group ----
#pragma unroll
        for (int j = 0; j < 4; ++j) {
#pragma unroll
            for (int x = 1; x < 16; x <<= 1) {
                sgp[j] += __shfl_xor(sgp[j], x);
                slp[j] += __shfl_xor(slp[j], x);
            }
        }
#pragma unroll
        for (int nd = 0; nd < 8; ++nd)
#pragma unroll
            for (int j = 0; j < 4; ++j) {
                int q = q0w + lhi * 4 + j;
                float v = 0.5f * (og[nd][j] / sgp[j] + ol[nd][j] / slp[j]);
                att[(size_t)q * CDIM + h * DHEAD + nd * 16 + l15] = (__bf16)v;
            }
    }
}

// ---------------- launcher ----------------
extern "C" void kernel_launch(void* const* d_in, const int* in_sizes, int n_in,
                              void* d_out, int out_size, void* d_ws, size_t ws_size,
                              hipStream_t stream) {
    const float* x  = (const float*)d_in[0];
    const float* wq = (const float*)d_in[1];
    const float* wk = (const float*)d_in[2];
    const float* wv = (const float*)d_in[3];
    const float* wo = (const float*)d_in[4];
    char* ws = (char*)d_ws;

    __bf16* xbf   = (__bf16*)(ws + 0);          // 8 MB
    __bf16* wqkvT = (__bf16*)(ws + 8388608);    // 12 MB  [3072][2048]
    __bf16* woT   = (__bf16*)(ws + 20971520);   // 8 MB   [2048][2048]
    __bf16* qkv   = (__bf16*)(ws + 29360128);   // 12 MB  [2048][3072]
    __bf16* Q     = (__bf16*)(ws + 41943040);   // 8 MB   [16][2048][128]
    __bf16* K     = (__bf16*)(ws + 50331648);   // 2 MB   [4][2048][128]
    __bf16* VT    = (__bf16*)(ws + 52428800);   // 2 MB   [4][128][2048]
    __bf16* att   = (__bf16*)(ws + 54525952);   // 8 MB   [2048][2048]
    float*  tab   = (float*)(ws + 62914560);    // 1 MB   [2048][64][2]

    k_cvt<<<4096, 256, 0, stream>>>(x, xbf, 1048576);
    k_tpose<float><<<dim3(64, 64), dim3(32, 8), 0, stream>>>(wq, 2048, wqkvT, 2048, 2048, 2048);
    k_tpose<float><<<dim3(16, 64), dim3(32, 8), 0, stream>>>(wk, 512, wqkvT + (size_t)2048 * 2048, 2048, 2048, 512);
    k_tpose<float><<<dim3(16, 64), dim3(32, 8), 0, stream>>>(wv, 512, wqkvT + (size_t)2560 * 2048, 2048, 2048, 512);
    k_tpose<float><<<dim3(64, 64), dim3(32, 8), 0, stream>>>(wo, 2048, woT, 2048, 2048, 2048);
    k_rtab<<<512, 256, 0, stream>>>(tab);
    k_gemm_bt<true><<<dim3(24, 16), 256, 0, stream>>>(xbf, wqkvT, qkv, 2048, 3072, 2048, 3072);
    k_rope<<<10240, 256, 0, stream>>>(qkv, tab, Q, K);
    k_tpose<__bf16><<<dim3(16, 64), dim3(32, 8), 0, stream>>>(qkv + 2560, 3072, VT, 2048, 2048, 512);
    k_attn<<<dim3(16, 16), 512, 0, stream>>>(Q, K, VT, att);
    k_gemm_bt<false><<<dim3(16, 16), 256, 0, stream>>>(att, woT, d_out, 2048, 2048, 2048, 2048);
}

// Round 4
// 321.074 us; speedup vs baseline: 4.8481x; 4.8481x over previous
//
#include <hip/hip_runtime.h>
#include <hip/hip_bf16.h>
#include <cstdint>
#include <cstddef>

#define T_SEQ 2048
#define CDIM  2048
#define HQ    16
#define HKV   4
#define DHEAD 128
#define NQKV  3072   // q(2048) | k(512) | v(512)

typedef __bf16 bf8 __attribute__((ext_vector_type(8)));
typedef __bf16 bf4 __attribute__((ext_vector_type(4)));
typedef float  f4  __attribute__((ext_vector_type(4)));

static __device__ __forceinline__ f4 mfma16(bf8 a, bf8 b, f4 c) {
    return __builtin_amdgcn_mfma_f32_16x16x32_bf16(a, b, c, 0, 0, 0);
}

#define GLOAD16(g, l)                                                        \
    __builtin_amdgcn_global_load_lds(                                        \
        (const __attribute__((address_space(1))) void*)(g),                  \
        (__attribute__((address_space(3))) void*)(l), 16, 0, 0)

static __device__ __forceinline__ float toF(float v) { return v; }
static __device__ __forceinline__ float toF(__bf16 v) { return (float)v; }

// ---------------- fp32 -> bf16 elementwise (x) ----------------
__global__ __launch_bounds__(256) void k_cvt(const float* __restrict__ in,
                                             __bf16* __restrict__ out, int n4) {
    int i = blockIdx.x * 256 + threadIdx.x;
    if (i >= n4) return;
    float4 v = ((const float4*)in)[i];
    bf4 o;
    o[0] = (__bf16)v.x; o[1] = (__bf16)v.y; o[2] = (__bf16)v.z; o[3] = (__bf16)v.w;
    ((bf4*)out)[i] = o;
}

// ---------------- transpose + convert: dst[c][r] = src[r][c] ----------------
template <typename TS>
__global__ __launch_bounds__(256) void k_tpose(const TS* __restrict__ src, int ld_src,
                                               __bf16* __restrict__ dst, int ld_dst,
                                               int R, int C) {
    __shared__ float tile[32][33];
    const int c0 = blockIdx.x * 32, r0 = blockIdx.y * 32;
    const int tx = threadIdx.x, ty = threadIdx.y;
#pragma unroll
    for (int i = 0; i < 4; ++i)
        tile[ty + i * 8][tx] = toF(src[(size_t)(r0 + ty + i * 8) * ld_src + c0 + tx]);
    __syncthreads();
#pragma unroll
    for (int i = 0; i < 4; ++i)
        dst[(size_t)(c0 + ty + i * 8) * ld_dst + r0 + tx] = (__bf16)tile[tx][ty + i * 8];
}

// ---------------- RoPE cos/sin table [T][64][2] ----------------
__global__ __launch_bounds__(256) void k_rtab(float* __restrict__ tab) {
    int idx = blockIdx.x * 256 + threadIdx.x;  // T*64
    int t = idx >> 6, j = idx & 63;
    float invf = expf(-(float)j * (9.210340371976184f / 64.0f));  // 10000^(-j/64)
    float a = (float)t * invf;
    tab[idx * 2 + 0] = cosf(a);
    tab[idx * 2 + 1] = sinf(a);
}

// ---------------- RoPE apply: qkv(bf16) -> Q [H][T][D], K [HKV][T][D] ----------------
__global__ __launch_bounds__(256) void k_rope(const __bf16* __restrict__ qkv,
                                              const float* __restrict__ tab,
                                              __bf16* __restrict__ Q,
                                              __bf16* __restrict__ K) {
    int idx = blockIdx.x * 256 + threadIdx.x;  // T * 20 * 64
    int j = idx & 63;
    int hd = (idx >> 6) % 20;
    int t = idx / (20 * 64);
    const __bf16* base;
    __bf16* dst;
    if (hd < HQ) {
        base = qkv + (size_t)t * NQKV + hd * DHEAD;
        dst = Q + ((size_t)hd * T_SEQ + t) * DHEAD;
    } else {
        int kvh = hd - HQ;
        base = qkv + (size_t)t * NQKV + CDIM + kvh * DHEAD;
        dst = K + ((size_t)kvh * T_SEQ + t) * DHEAD;
    }
    float a = (float)base[j], b = (float)base[j + 64];
    float c = tab[(t * 64 + j) * 2 + 0];
    float s = tab[(t * 64 + j) * 2 + 1];
    dst[j] = (__bf16)(a * c - b * s);
    dst[j + 64] = (__bf16)(b * c + a * s);
}

// ---------------- GEMM (m97-style): C[M][N] = A[M][K] * BT[N][K]^T ----------------
// 128x128 tile, BK=32, global_load_lds(16B) staging, XOR-swizzled LDS
// (pre-swizzled global source, linear LDS dest; read applies same XOR).
template <bool OBF>
__global__ __launch_bounds__(256) void k_gemm_bt(const __bf16* __restrict__ A,
                                                 const __bf16* __restrict__ BT,
                                                 void* __restrict__ C,
                                                 int M, int N, int K, int ldc) {
    __shared__ __bf16 Al[128 * 32];  // linear, 64B rows
    __shared__ __bf16 Bl[128 * 32];
    const int tid = threadIdx.x;
    const int wid = tid >> 6, lane = tid & 63;
    const int l15 = lane & 15, lhi = lane >> 4;
    const int wr = wid >> 1, wc = wid & 1;
    const size_t arow0 = (size_t)blockIdx.y * 128;
    const size_t brow0 = (size_t)blockIdx.x * 128;

    const int srow = wid * 16 + (lane >> 2);
    const int scol = ((lane & 3) ^ ((lane >> 3) & 3)) * 8;
    const __bf16* Ag0 = A + (arow0 + srow) * K + scol;
    const __bf16* Ag1 = Ag0 + (size_t)64 * K;
    const __bf16* Bg0 = BT + (brow0 + srow) * K + scol;
    const __bf16* Bg1 = Bg0 + (size_t)64 * K;
    char* AlB = (char*)&Al[0];
    char* BlB = (char*)&Bl[0];

    f4 acc[4][4] = {};
    const int c16 = (lhi ^ ((l15 >> 1) & 3)) * 16;

    for (int k0 = 0; k0 < K; k0 += 32) {
        GLOAD16(Ag0 + k0, AlB + wid * 1024);
        GLOAD16(Ag1 + k0, AlB + 4096 + wid * 1024);
        GLOAD16(Bg0 + k0, BlB + wid * 1024);
        GLOAD16(Bg1 + k0, BlB + 4096 + wid * 1024);
        __syncthreads();
        bf8 af[4], bfr[4];
#pragma unroll
        for (int m = 0; m < 4; ++m) {
            int r = wr * 64 + m * 16 + l15;
            af[m] = *(const bf8*)(AlB + r * 64 + c16);
        }
#pragma unroll
        for (int n = 0; n < 4; ++n) {
            int r = wc * 64 + n * 16 + l15;
            bfr[n] = *(const bf8*)(BlB + r * 64 + c16);
        }
#pragma unroll
        for (int m = 0; m < 4; ++m)
#pragma unroll
            for (int n = 0; n < 4; ++n)
                acc[m][n] = mfma16(af[m], bfr[n], acc[m][n]);
        __syncthreads();
    }

    const int row0 = blockIdx.y * 128 + wr * 64, col0 = blockIdx.x * 128 + wc * 64;
#pragma unroll
    for (int m = 0; m < 4; ++m)
#pragma unroll
        for (int n = 0; n < 4; ++n)
#pragma unroll
            for (int j = 0; j < 4; ++j) {
                int r = row0 + m * 16 + lhi * 4 + j;
                int c = col0 + n * 16 + l15;
                float v = acc[m][n][j];
                if (OBF)
                    ((__bf16*)C)[(size_t)r * ldc + c] = (__bf16)v;
                else
                    ((float*)C)[(size_t)r * ldc + c] = v;
            }
}

// ---------------- dual-softmax flash attention (LDS-staged, 64-key tiles) ----------------
// grid (32,16), 256 thr (4 waves x 16 q-rows). qt = 31-bx so heavy blocks go first.
// Shared-exp dual softmax, defer-max, T14 reg-prefetch staging, 2 barriers/tile.
__global__ __launch_bounds__(256) void k_attn(const __bf16* __restrict__ Q,
                                              const __bf16* __restrict__ Kr,
                                              const __bf16* __restrict__ VT,
                                              __bf16* __restrict__ att) {
    __shared__ __bf16 Kl[64][136];     // [key][d + pad]
    __shared__ __bf16 Vl[128][72];     // [d][key + pad]
    __shared__ __bf16 Pl[4][16][72];   // per-wave P transpose (global)
    __shared__ __bf16 Pw[4][16][72];   // per-wave P transpose (local partial)
    const int h = blockIdx.y, kvh = h >> 2;
    const int qt = 31 - (int)blockIdx.x;
    const int tid = threadIdx.x, wid = tid >> 6, lane = tid & 63;
    const int l15 = lane & 15, lhi = lane >> 4;
    const int q0w = qt * 64 + wid * 16;
    const int NT = qt + 1;
    const int iblk = (qt >> 2) << 8;
    const int kst = iblk >= 128 ? iblk - 128 : 0;
    const int off = iblk - kst;
    const float scale = 0.08838834764831845f;  // 1/sqrt(128)
    const float L2E = 1.44269504088896340736f;
    const float THR = 5.545177444479562f;      // 8*ln2 -> p <= 256

    // staging: each thread moves 64B of K (row krow) and 64B of V (row vrow)
    const int krow = tid >> 2, kcol = (tid & 3) * 32;
    const int vrow = tid >> 1, vcol = (tid & 1) * 32;
    const __bf16* Kg = Kr + ((size_t)kvh * T_SEQ + krow) * DHEAD + kcol;
    const __bf16* Vg = VT + ((size_t)kvh * DHEAD + vrow) * T_SEQ + vcol;

    bf8 qf[4];
#pragma unroll
    for (int dc = 0; dc < 4; ++dc)
        qf[dc] = *(const bf8*)&Q[((size_t)h * T_SEQ + q0w + l15) * DHEAD + dc * 32 + lhi * 8];

    f4 og[8] = {}, ol[8] = {};
    float mg[4], sgp[4], slp[4];
#pragma unroll
    for (int j = 0; j < 4; ++j) { mg[j] = -__builtin_inff(); sgp[j] = slp[j] = 0.f; }

    bf8 kp[4], vp[4];
#pragma unroll
    for (int c = 0; c < 4; ++c) {
        kp[c] = *(const bf8*)(Kg + c * 8);
        vp[c] = *(const bf8*)(Vg + c * 8);
    }
#pragma unroll
    for (int c = 0; c < 4; ++c) {
        *(bf8*)&Kl[krow][kcol + c * 8] = kp[c];
        *(bf8*)&Vl[vrow][vcol + c * 8] = vp[c];
    }
    __syncthreads();

    for (int kt = 0; kt < NT; ++kt) {
        const int kb = kt * 64;
        // T14: issue next tile's global loads before compute
        if (kt + 1 < NT) {
#pragma unroll
            for (int c = 0; c < 4; ++c) {
                kp[c] = *(const bf8*)(Kg + (size_t)(kb + 64) * DHEAD + c * 8);
                vp[c] = *(const bf8*)(Vg + kb + 64 + c * 8);
            }
        }
        // ---- QK^T over 64 keys ----
        f4 sc[4] = {};
#pragma unroll
        for (int ks = 0; ks < 4; ++ks)
#pragma unroll
            for (int dc = 0; dc < 4; ++dc) {
                bf8 kf = *(const bf8*)&Kl[ks * 16 + l15][dc * 32 + lhi * 8];
                sc[ks] = mfma16(qf[dc], kf, sc[ks]);
            }
        const bool interior = (kb + 63 <= q0w);
        const int d0 = kb + l15 - q0w;   // key(ks=0) - q0w
        float p[4][4], psum[4];
#pragma unroll
        for (int j = 0; j < 4; ++j) {
            const int rq = lhi * 4 + j;
            float s0 = sc[0][j] * scale;
            float s1 = sc[1][j] * scale;
            float s2 = sc[2][j] * scale;
            float s3 = sc[3][j] * scale;
            if (!interior) {
                if (d0 > rq) s0 = -3.0e38f;
                if (d0 + 16 > rq) s1 = -3.0e38f;
                if (d0 + 32 > rq) s2 = -3.0e38f;
                if (d0 + 48 > rq) s3 = -3.0e38f;
            }
            float mx = fmaxf(fmaxf(s0, s1), fmaxf(s2, s3));
            if (!__all(mx <= mg[j] + THR)) {
                float m2 = mx;
#pragma unroll
                for (int x = 1; x < 16; x <<= 1) m2 = fmaxf(m2, __shfl_xor(m2, x));
                float mn = fmaxf(mg[j], m2);
                float f = exp2f((mg[j] - mn) * L2E);
                mg[j] = mn;
                sgp[j] *= f; slp[j] *= f;
#pragma unroll
                for (int nd = 0; nd < 8; ++nd) { og[nd][j] *= f; ol[nd][j] *= f; }
            }
            const float mref = mg[j];
            p[0][j] = exp2f((s0 - mref) * L2E);
            p[1][j] = exp2f((s1 - mref) * L2E);
            p[2][j] = exp2f((s2 - mref) * L2E);
            p[3][j] = exp2f((s3 - mref) * L2E);
            psum[j] = (p[0][j] + p[1][j]) + (p[2][j] + p[3][j]);
            sgp[j] += psum[j];
        }
        // ---- P transpose (global branch) ----
#pragma unroll
        for (int j = 0; j < 4; ++j)
#pragma unroll
            for (int ks = 0; ks < 4; ++ks)
                Pl[wid][lhi * 4 + j][ks * 16 + l15] = (__bf16)p[ks][j];
        bf8 pf0 = *(const bf8*)&Pl[wid][l15][lhi * 8];
        bf8 pf1 = *(const bf8*)&Pl[wid][l15][32 + lhi * 8];
        // ---- local branch ----
        const bool lact = (kb <= q0w + 15 - off) && (kb + 63 >= kst);
        const bool lfull = lact && (kb >= kst) && (kb + 63 <= q0w - off);
        bf8 pl0 = pf0, pl1 = pf1;
        if (lact) {
            if (lfull) {
#pragma unroll
                for (int j = 0; j < 4; ++j) slp[j] += psum[j];
            } else {
                const int kk = kb + l15;
#pragma unroll
                for (int j = 0; j < 4; ++j) {
                    const int up = lhi * 4 + j - off;  // key-offset bound: d <= up
                    float l0 = (kk >= kst && d0 <= up) ? p[0][j] : 0.f;
                    float l1 = (kk + 16 >= kst && d0 + 16 <= up) ? p[1][j] : 0.f;
                    float l2 = (kk + 32 >= kst && d0 + 32 <= up) ? p[2][j] : 0.f;
                    float l3 = (kk + 48 >= kst && d0 + 48 <= up) ? p[3][j] : 0.f;
                    slp[j] += (l0 + l1) + (l2 + l3);
                    Pw[wid][lhi * 4 + j][l15] = (__bf16)l0;
                    Pw[wid][lhi * 4 + j][16 + l15] = (__bf16)l1;
                    Pw[wid][lhi * 4 + j][32 + l15] = (__bf16)l2;
                    Pw[wid][lhi * 4 + j][48 + l15] = (__bf16)l3;
                }
                pl0 = *(const bf8*)&Pw[wid][l15][lhi * 8];
                pl1 = *(const bf8*)&Pw[wid][l15][32 + lhi * 8];
            }
        }
        // ---- PV (shared V fragments) ----
#pragma unroll
        for (int nd = 0; nd < 8; ++nd) {
            bf8 v0 = *(const bf8*)&Vl[nd * 16 + l15][lhi * 8];
            bf8 v1 = *(const bf8*)&Vl[nd * 16 + l15][32 + lhi * 8];
            og[nd] = mfma16(pf0, v0, og[nd]);
            og[nd] = mfma16(pf1, v1, og[nd]);
            if (lact) {
                ol[nd] = mfma16(pl0, v0, ol[nd]);
                ol[nd] = mfma16(pl1, v1, ol[nd]);
            }
        }
        __syncthreads();
        if (kt + 1 < NT) {
#pragma unroll
            for (int c = 0; c < 4; ++c) {
                *(bf8*)&Kl[krow][kcol + c * 8] = kp[c];
                *(bf8*)&Vl[vrow][vcol + c * 8] = vp[c];
            }
            __syncthreads();
        }
    }

    // single final denominator reduction across the 16-lane group
#pragma unroll
    for (int j = 0; j < 4; ++j) {
#pragma unroll
        for (int x = 1; x < 16; x <<= 1) {
            sgp[j] += __shfl_xor(sgp[j], x);
            slp[j] += __shfl_xor(slp[j], x);
        }
        sgp[j] = 1.f / sgp[j];
        slp[j] = 1.f / slp[j];
    }
#pragma unroll
    for (int nd = 0; nd < 8; ++nd)
#pragma unroll
        for (int j = 0; j < 4; ++j) {
            int q = q0w + lhi * 4 + j;
            float v = 0.5f * (og[nd][j] * sgp[j] + ol[nd][j] * slp[j]);
            att[(size_t)q * CDIM + h * DHEAD + nd * 16 + l15] = (__bf16)v;
        }
}

// ---------------- launcher ----------------
extern "C" void kernel_launch(void* const* d_in, const int* in_sizes, int n_in,
                              void* d_out, int out_size, void* d_ws, size_t ws_size,
                              hipStream_t stream) {
    const float* x  = (const float*)d_in[0];
    const float* wq = (const float*)d_in[1];
    const float* wk = (const float*)d_in[2];
    const float* wv = (const float*)d_in[3];
    const float* wo = (const float*)d_in[4];
    char* ws = (char*)d_ws;

    __bf16* xbf   = (__bf16*)(ws + 0);          // 8 MB
    __bf16* wqkvT = (__bf16*)(ws + 8388608);    // 12 MB  [3072][2048]
    __bf16* woT   = (__bf16*)(ws + 20971520);   // 8 MB   [2048][2048]
    __bf16* qkv   = (__bf16*)(ws + 29360128);   // 12 MB  [2048][3072]
    __bf16* Q     = (__bf16*)(ws + 41943040);   // 8 MB   [16][2048][128]
    __bf16* K     = (__bf16*)(ws + 50331648);   // 2 MB   [4][2048][128]
    __bf16* VT    = (__bf16*)(ws + 52428800);   // 2 MB   [4][128][2048]
    __bf16* att   = (__bf16*)(ws + 54525952);   // 8 MB   [2048][2048]
    float*  tab   = (float*)(ws + 62914560);    // 1 MB   [2048][64][2]

    k_cvt<<<4096, 256, 0, stream>>>(x, xbf, 1048576);
    k_tpose<float><<<dim3(64, 64), dim3(32, 8), 0, stream>>>(wq, 2048, wqkvT, 2048, 2048, 2048);
    k_tpose<float><<<dim3(16, 64), dim3(32, 8), 0, stream>>>(wk, 512, wqkvT + (size_t)2048 * 2048, 2048, 2048, 512);
    k_tpose<float><<<dim3(16, 64), dim3(32, 8), 0, stream>>>(wv, 512, wqkvT + (size_t)2560 * 2048, 2048, 2048, 512);
    k_tpose<float><<<dim3(64, 64), dim3(32, 8), 0, stream>>>(wo, 2048, woT, 2048, 2048, 2048);
    k_rtab<<<512, 256, 0, stream>>>(tab);
    k_gemm_bt<true><<<dim3(24, 16), 256, 0, stream>>>(xbf, wqkvT, qkv, 2048, 3072, 2048, 3072);
    k_rope<<<10240, 256, 0, stream>>>(qkv, tab, Q, K);
    k_tpose<__bf16><<<dim3(16, 64), dim3(32, 8), 0, stream>>>(qkv + 2560, 3072, VT, 2048, 2048, 512);
    k_attn<<<dim3(32, 16), 256, 0, stream>>>(Q, K, VT, att);
    k_gemm_bt<false><<<dim3(16, 16), 256, 0, stream>>>(att, woT, d_out, 2048, 2048, 2048, 2048);
}

// Round 5
// 273.331 us; speedup vs baseline: 5.6949x; 1.1747x over previous
//
#include <hip/hip_runtime.h>
#include <hip/hip_bf16.h>
#include <cstdint>
#include <cstddef>

#define T_SEQ 2048
#define CDIM  2048
#define HQ    16
#define HKV   4
#define DHEAD 128
#define NQKV  3072   // q(2048) | k(512) | v(512)

typedef __bf16 bf8 __attribute__((ext_vector_type(8)));
typedef __bf16 bf4 __attribute__((ext_vector_type(4)));
typedef float  f4  __attribute__((ext_vector_type(4)));

static __device__ __forceinline__ f4 mfma16(bf8 a, bf8 b, f4 c) {
    return __builtin_amdgcn_mfma_f32_16x16x32_bf16(a, b, c, 0, 0, 0);
}

#define GLOAD16(g, l)                                                        \
    __builtin_amdgcn_global_load_lds(                                        \
        (const __attribute__((address_space(1))) void*)(g),                  \
        (__attribute__((address_space(3))) void*)(l), 16, 0, 0)

static __device__ __forceinline__ float toF(float v) { return v; }
static __device__ __forceinline__ float toF(__bf16 v) { return (float)v; }

// ---------------- fp32 -> bf16 elementwise (x) ----------------
__global__ __launch_bounds__(256) void k_cvt(const float* __restrict__ in,
                                             __bf16* __restrict__ out, int n4) {
    int i = blockIdx.x * 256 + threadIdx.x;
    if (i >= n4) return;
    float4 v = ((const float4*)in)[i];
    bf4 o;
    o[0] = (__bf16)v.x; o[1] = (__bf16)v.y; o[2] = (__bf16)v.z; o[3] = (__bf16)v.w;
    ((bf4*)out)[i] = o;
}

// ---------------- transpose + convert: dst[c][r] = src[r][c] ----------------
template <typename TS>
__global__ __launch_bounds__(256) void k_tpose(const TS* __restrict__ src, int ld_src,
                                               __bf16* __restrict__ dst, int ld_dst,
                                               int R, int C) {
    __shared__ float tile[32][33];
    const int c0 = blockIdx.x * 32, r0 = blockIdx.y * 32;
    const int tx = threadIdx.x, ty = threadIdx.y;
#pragma unroll
    for (int i = 0; i < 4; ++i)
        tile[ty + i * 8][tx] = toF(src[(size_t)(r0 + ty + i * 8) * ld_src + c0 + tx]);
    __syncthreads();
#pragma unroll
    for (int i = 0; i < 4; ++i)
        dst[(size_t)(c0 + ty + i * 8) * ld_dst + r0 + tx] = (__bf16)tile[tx][ty + i * 8];
}

// ---------------- RoPE cos/sin table [T][64][2] ----------------
__global__ __launch_bounds__(256) void k_rtab(float* __restrict__ tab) {
    int idx = blockIdx.x * 256 + threadIdx.x;  // T*64
    int t = idx >> 6, j = idx & 63;
    float invf = expf(-(float)j * (9.210340371976184f / 64.0f));  // 10000^(-j/64)
    float a = (float)t * invf;
    tab[idx * 2 + 0] = cosf(a);
    tab[idx * 2 + 1] = sinf(a);
}

// ---------------- RoPE apply: qkv(bf16) -> Q [H][T][D], K [HKV][T][D] ----------------
__global__ __launch_bounds__(256) void k_rope(const __bf16* __restrict__ qkv,
                                              const float* __restrict__ tab,
                                              __bf16* __restrict__ Q,
                                              __bf16* __restrict__ K) {
    int idx = blockIdx.x * 256 + threadIdx.x;  // T * 20 * 64
    int j = idx & 63;
    int hd = (idx >> 6) % 20;
    int t = idx / (20 * 64);
    const __bf16* base;
    __bf16* dst;
    if (hd < HQ) {
        base = qkv + (size_t)t * NQKV + hd * DHEAD;
        dst = Q + ((size_t)hd * T_SEQ + t) * DHEAD;
    } else {
        int kvh = hd - HQ;
        base = qkv + (size_t)t * NQKV + CDIM + kvh * DHEAD;
        dst = K + ((size_t)kvh * T_SEQ + t) * DHEAD;
    }
    float a = (float)base[j], b = (float)base[j + 64];
    float c = tab[(t * 64 + j) * 2 + 0];
    float s = tab[(t * 64 + j) * 2 + 1];
    dst[j] = (__bf16)(a * c - b * s);
    dst[j + 64] = (__bf16)(b * c + a * s);
}

// ---------------- GEMM (m97-style): C[M][N] = A[M][K] * BT[N][K]^T ----------------
template <bool OBF>
__global__ __launch_bounds__(256) void k_gemm_bt(const __bf16* __restrict__ A,
                                                 const __bf16* __restrict__ BT,
                                                 void* __restrict__ C,
                                                 int M, int N, int K, int ldc) {
    __shared__ __bf16 Al[128 * 32];  // linear, 64B rows
    __shared__ __bf16 Bl[128 * 32];
    const int tid = threadIdx.x;
    const int wid = tid >> 6, lane = tid & 63;
    const int l15 = lane & 15, lhi = lane >> 4;
    const int wr = wid >> 1, wc = wid & 1;
    const size_t arow0 = (size_t)blockIdx.y * 128;
    const size_t brow0 = (size_t)blockIdx.x * 128;

    const int srow = wid * 16 + (lane >> 2);
    const int scol = ((lane & 3) ^ ((lane >> 3) & 3)) * 8;
    const __bf16* Ag0 = A + (arow0 + srow) * K + scol;
    const __bf16* Ag1 = Ag0 + (size_t)64 * K;
    const __bf16* Bg0 = BT + (brow0 + srow) * K + scol;
    const __bf16* Bg1 = Bg0 + (size_t)64 * K;
    char* AlB = (char*)&Al[0];
    char* BlB = (char*)&Bl[0];

    f4 acc[4][4] = {};
    const int c16 = (lhi ^ ((l15 >> 1) & 3)) * 16;

    for (int k0 = 0; k0 < K; k0 += 32) {
        GLOAD16(Ag0 + k0, AlB + wid * 1024);
        GLOAD16(Ag1 + k0, AlB + 4096 + wid * 1024);
        GLOAD16(Bg0 + k0, BlB + wid * 1024);
        GLOAD16(Bg1 + k0, BlB + 4096 + wid * 1024);
        __syncthreads();
        bf8 af[4], bfr[4];
#pragma unroll
        for (int m = 0; m < 4; ++m) {
            int r = wr * 64 + m * 16 + l15;
            af[m] = *(const bf8*)(AlB + r * 64 + c16);
        }
#pragma unroll
        for (int n = 0; n < 4; ++n) {
            int r = wc * 64 + n * 16 + l15;
            bfr[n] = *(const bf8*)(BlB + r * 64 + c16);
        }
#pragma unroll
        for (int m = 0; m < 4; ++m)
#pragma unroll
            for (int n = 0; n < 4; ++n)
                acc[m][n] = mfma16(af[m], bfr[n], acc[m][n]);
        __syncthreads();
    }

    const int row0 = blockIdx.y * 128 + wr * 64, col0 = blockIdx.x * 128 + wc * 64;
#pragma unroll
    for (int m = 0; m < 4; ++m)
#pragma unroll
        for (int n = 0; n < 4; ++n)
#pragma unroll
            for (int j = 0; j < 4; ++j) {
                int r = row0 + m * 16 + lhi * 4 + j;
                int c = col0 + n * 16 + l15;
                float v = acc[m][n][j];
                if (OBF)
                    ((__bf16*)C)[(size_t)r * ldc + c] = (__bf16)v;
                else
                    ((float*)C)[(size_t)r * ldc + c] = v;
            }
}

// ---------------- dual-softmax flash attention, lean phase-split ----------------
// grid (32,16), 256 thr (4 waves x 16 q-rows), qt = 31-bx (heavy first).
// Interior tiles: branch-free softmax (fma+exp per score). Causal mask only in
// last tile. Exactly one masked-local tile (qt-2); full-window tiles switch the
// PV accumulator (oc = non-window causal part, ow = window part).
// K/V LDS XOR-swizzled (conflict-free frag reads). Shared exponents, defer-max.
__global__ __launch_bounds__(256) void k_attn(const __bf16* __restrict__ Q,
                                              const __bf16* __restrict__ Kr,
                                              const __bf16* __restrict__ VT,
                                              __bf16* __restrict__ att) {
    __shared__ __bf16 Kl[64 * 128];    // [key][d], rows 256B, XOR-swizzled
    __shared__ __bf16 Vl[128 * 64];    // [d][key], rows 128B, XOR-swizzled
    __shared__ __bf16 Pl[4][16][72];   // per-wave P (or complement at partial tile)
    __shared__ __bf16 Pw[4][16][72];   // per-wave masked-local P (partial tile)
    const int h = blockIdx.y, kvh = h >> 2;
    const int qt = 31 - (int)blockIdx.x;
    const int tid = threadIdx.x, wid = tid >> 6, lane = tid & 63;
    const int l15 = lane & 15, lhi = lane >> 4;
    const int q0w = qt * 64 + wid * 16;
    const bool hasloc = qt >= 4;                 // qt<4: local mask == causal mask
    const int lfLo = 4 * (qt >> 2) - 2;          // first window tile (qt>=4)
    const int lpart = qt - 2;                    // the single masked-local tile
    const float CE = 0.12751741f;                // (1/sqrt(128)) * log2(e)
    const float L2E = 1.44269504f;
    const float SCL = 0.08838834764831845f;
    const float THR = 5.5451774f;                // 8*ln2

    char* KlB = (char*)&Kl[0];
    char* VlB = (char*)&Vl[0];
    const int krow = tid >> 2, kcolb = (tid & 3) * 64;
    const int kswz = (krow & 7) << 4;
    const int vrow = tid >> 1, vcolb = (tid & 1) * 64;
    const int vswz = (vrow & 7) << 4;
    const int fswz = (l15 & 7) << 4;
    const __bf16* Kg = Kr + ((size_t)kvh * T_SEQ + krow) * DHEAD + (tid & 3) * 32;
    const __bf16* Vg = VT + ((size_t)kvh * DHEAD + vrow) * T_SEQ + (tid & 1) * 32;

    bf8 qf[4];
#pragma unroll
    for (int dc = 0; dc < 4; ++dc)
        qf[dc] = *(const bf8*)&Q[((size_t)h * T_SEQ + q0w + l15) * DHEAD + dc * 32 + lhi * 8];

    f4 oc[8] = {}, ow[8] = {};
    float mg[4], sgp[4], slp[4];
#pragma unroll
    for (int j = 0; j < 4; ++j) { mg[j] = -__builtin_inff(); sgp[j] = slp[j] = 0.f; }
    float mgmin = -__builtin_inff();

    // stage tile 0
    bf8 kp[4], vp[4];
#pragma unroll
    for (int c = 0; c < 4; ++c) {
        kp[c] = *(const bf8*)(Kg + c * 8);
        vp[c] = *(const bf8*)(Vg + c * 8);
    }
#pragma unroll
    for (int c = 0; c < 4; ++c) {
        *(bf8*)(KlB + krow * 256 + ((kcolb + c * 16) ^ kswz)) = kp[c];
        *(bf8*)(VlB + vrow * 128 + ((vcolb + c * 16) ^ vswz)) = vp[c];
    }
    __syncthreads();

    for (int kt = 0; kt <= qt; ++kt) {
        const int kb = kt * 64;
        const bool last = (kt == qt);
        if (!last) {  // T14: issue next tile's global loads before compute
#pragma unroll
            for (int c = 0; c < 4; ++c) {
                kp[c] = *(const bf8*)(Kg + (size_t)(kb + 64) * DHEAD + c * 8);
                vp[c] = *(const bf8*)(Vg + kb + 64 + c * 8);
            }
        }
        // ---- QK^T ----
        f4 sc[4] = {};
        __builtin_amdgcn_s_setprio(1);
#pragma unroll
        for (int ks = 0; ks < 4; ++ks)
#pragma unroll
            for (int dc = 0; dc < 4; ++dc) {
                bf8 kf = *(const bf8*)(KlB + (ks * 16 + l15) * 256 + ((dc * 64 + lhi * 16) ^ fswz));
                sc[ks] = mfma16(qf[dc], kf, sc[ks]);
            }
        __builtin_amdgcn_s_setprio(0);

        float t[4][4];
#pragma unroll
        for (int ks = 0; ks < 4; ++ks)
#pragma unroll
            for (int j = 0; j < 4; ++j) t[ks][j] = sc[ks][j];
        if (last) {  // causal mask (only tile that needs it)
#pragma unroll
            for (int ks = 0; ks < 4; ++ks)
#pragma unroll
                for (int j = 0; j < 4; ++j)
                    if (kb + ks * 16 + l15 > q0w + lhi * 4 + j) t[ks][j] = -3.0e38f;
        }
        // ---- single defer-max gate ----
        float mx = t[0][0];
#pragma unroll
        for (int ks = 0; ks < 4; ++ks)
#pragma unroll
            for (int j = 0; j < 4; ++j) mx = fmaxf(mx, t[ks][j]);
        mx *= SCL;
        if (!__all(mx <= mgmin + THR)) {
#pragma unroll
            for (int j = 0; j < 4; ++j) {
                float m2 = fmaxf(fmaxf(t[0][j], t[1][j]), fmaxf(t[2][j], t[3][j])) * SCL;
#pragma unroll
                for (int x = 1; x < 16; x <<= 1) m2 = fmaxf(m2, __shfl_xor(m2, x));
                float mn = fmaxf(mg[j], m2);
                float f = __builtin_amdgcn_exp2f((mg[j] - mn) * L2E);
                mg[j] = mn;
                sgp[j] *= f; slp[j] *= f;
#pragma unroll
                for (int nd = 0; nd < 8; ++nd) { oc[nd][j] *= f; ow[nd][j] *= f; }
            }
            mgmin = fminf(fminf(mg[0], mg[1]), fminf(mg[2], mg[3]));
        }
        // ---- branch-free exp ----
        float p[4][4], psum[4];
#pragma unroll
        for (int j = 0; j < 4; ++j) {
            const float bj = mg[j] * L2E;
#pragma unroll
            for (int ks = 0; ks < 4; ++ks)
                p[ks][j] = __builtin_amdgcn_exp2f(t[ks][j] * CE - bj);
            psum[j] = (p[0][j] + p[1][j]) + (p[2][j] + p[3][j]);
            sgp[j] += psum[j];
        }
        // ---- P stores ----
        const bool part = hasloc && (kt == lpart);
        if (!part) {
#pragma unroll
            for (int j = 0; j < 4; ++j)
#pragma unroll
                for (int ks = 0; ks < 4; ++ks)
                    Pl[wid][lhi * 4 + j][ks * 16 + l15] = (__bf16)p[ks][j];
        } else {
            const int e = q0w + lhi * 4 - 128 - kb - l15;  // window: ks*16 <= e+j
#pragma unroll
            for (int j = 0; j < 4; ++j) {
                float lsum = 0.f;
#pragma unroll
                for (int ks = 0; ks < 4; ++ks) {
                    float l = (ks * 16 <= e + j) ? p[ks][j] : 0.f;
                    lsum += l;
                    Pw[wid][lhi * 4 + j][ks * 16 + l15] = (__bf16)l;
                    Pl[wid][lhi * 4 + j][ks * 16 + l15] = (__bf16)(p[ks][j] - l);
                }
                slp[j] += lsum;
            }
        }
        const bool inwin = hasloc && kt >= lfLo && kt < lpart;
        if (inwin) {
#pragma unroll
            for (int j = 0; j < 4; ++j) slp[j] += psum[j];
        }
        // ---- PV ----
        bf8 pf0 = *(const bf8*)&Pl[wid][l15][lhi * 8];
        bf8 pf1 = *(const bf8*)&Pl[wid][l15][32 + lhi * 8];
        __builtin_amdgcn_s_setprio(1);
        if (part) {
            bf8 pw0 = *(const bf8*)&Pw[wid][l15][lhi * 8];
            bf8 pw1 = *(const bf8*)&Pw[wid][l15][32 + lhi * 8];
#pragma unroll
            for (int nd = 0; nd < 8; ++nd) {
                bf8 v0 = *(const bf8*)(VlB + (nd * 16 + l15) * 128 + ((lhi * 16) ^ fswz));
                bf8 v1 = *(const bf8*)(VlB + (nd * 16 + l15) * 128 + ((64 + lhi * 16) ^ fswz));
                oc[nd] = mfma16(pf0, v0, oc[nd]);
                oc[nd] = mfma16(pf1, v1, oc[nd]);
                ow[nd] = mfma16(pw0, v0, ow[nd]);
                ow[nd] = mfma16(pw1, v1, ow[nd]);
            }
        } else if (inwin) {
#pragma unroll
            for (int nd = 0; nd < 8; ++nd) {
                bf8 v0 = *(const bf8*)(VlB + (nd * 16 + l15) * 128 + ((lhi * 16) ^ fswz));
                bf8 v1 = *(const bf8*)(VlB + (nd * 16 + l15) * 128 + ((64 + lhi * 16) ^ fswz));
                ow[nd] = mfma16(pf0, v0, ow[nd]);
                ow[nd] = mfma16(pf1, v1, ow[nd]);
            }
        } else {
#pragma unroll
            for (int nd = 0; nd < 8; ++nd) {
                bf8 v0 = *(const bf8*)(VlB + (nd * 16 + l15) * 128 + ((lhi * 16) ^ fswz));
                bf8 v1 = *(const bf8*)(VlB + (nd * 16 + l15) * 128 + ((64 + lhi * 16) ^ fswz));
                oc[nd] = mfma16(pf0, v0, oc[nd]);
                oc[nd] = mfma16(pf1, v1, oc[nd]);
            }
        }
        __builtin_amdgcn_s_setprio(0);
        __syncthreads();
        if (!last) {
#pragma unroll
            for (int c = 0; c < 4; ++c) {
                *(bf8*)(KlB + krow * 256 + ((kcolb + c * 16) ^ kswz)) = kp[c];
                *(bf8*)(VlB + vrow * 128 + ((vcolb + c * 16) ^ vswz)) = vp[c];
            }
            __syncthreads();
        }
    }

    // ---- single final denominator reduction ----
#pragma unroll
    for (int j = 0; j < 4; ++j) {
#pragma unroll
        for (int x = 1; x < 16; x <<= 1) {
            sgp[j] += __shfl_xor(sgp[j], x);
            slp[j] += __shfl_xor(slp[j], x);
        }
    }
    float rg[4], rl[4];
#pragma unroll
    for (int j = 0; j < 4; ++j) {
        rg[j] = 1.f / sgp[j];
        rl[j] = hasloc ? 0.5f / slp[j] : 0.f;
    }
#pragma unroll
    for (int nd = 0; nd < 8; ++nd)
#pragma unroll
        for (int j = 0; j < 4; ++j) {
            int q = q0w + lhi * 4 + j;
            float go = oc[nd][j] + ow[nd][j];
            float v = hasloc ? (go * (0.5f * rg[j]) + ow[nd][j] * rl[j]) : go * rg[j];
            att[(size_t)q * CDIM + h * DHEAD + nd * 16 + l15] = (__bf16)v;
        }
}

// ---------------- launcher ----------------
extern "C" void kernel_launch(void* const* d_in, const int* in_sizes, int n_in,
                              void* d_out, int out_size, void* d_ws, size_t ws_size,
                              hipStream_t stream) {
    const float* x  = (const float*)d_in[0];
    const float* wq = (const float*)d_in[1];
    const float* wk = (const float*)d_in[2];
    const float* wv = (const float*)d_in[3];
    const float* wo = (const float*)d_in[4];
    char* ws = (char*)d_ws;

    __bf16* xbf   = (__bf16*)(ws + 0);          // 8 MB
    __bf16* wqkvT = (__bf16*)(ws + 8388608);    // 12 MB  [3072][2048]
    __bf16* woT   = (__bf16*)(ws + 20971520);   // 8 MB   [2048][2048]
    __bf16* qkv   = (__bf16*)(ws + 29360128);   // 12 MB  [2048][3072]
    __bf16* Q     = (__bf16*)(ws + 41943040);   // 8 MB   [16][2048][128]
    __bf16* K     = (__bf16*)(ws + 50331648);   // 2 MB   [4][2048][128]
    __bf16* VT    = (__bf16*)(ws + 52428800);   // 2 MB   [4][128][2048]
    __bf16* att   = (__bf16*)(ws + 54525952);   // 8 MB   [2048][2048]
    float*  tab   = (float*)(ws + 62914560);    // 1 MB   [2048][64][2]

    k_cvt<<<4096, 256, 0, stream>>>(x, xbf, 1048576);
    k_tpose<float><<<dim3(64, 64), dim3(32, 8), 0, stream>>>(wq, 2048, wqkvT, 2048, 2048, 2048);
    k_tpose<float><<<dim3(16, 64), dim3(32, 8), 0, stream>>>(wk, 512, wqkvT + (size_t)2048 * 2048, 2048, 2048, 512);
    k_tpose<float><<<dim3(16, 64), dim3(32, 8), 0, stream>>>(wv, 512, wqkvT + (size_t)2560 * 2048, 2048, 2048, 512);
    k_tpose<float><<<dim3(64, 64), dim3(32, 8), 0, stream>>>(wo, 2048, woT, 2048, 2048, 2048);
    k_rtab<<<512, 256, 0, stream>>>(tab);
    k_gemm_bt<true><<<dim3(24, 16), 256, 0, stream>>>(xbf, wqkvT, qkv, 2048, 3072, 2048, 3072);
    k_rope<<<10240, 256, 0, stream>>>(qkv, tab, Q, K);
    k_tpose<__bf16><<<dim3(16, 64), dim3(32, 8), 0, stream>>>(qkv + 2560, 3072, VT, 2048, 2048, 512);
    k_attn<<<dim3(32, 16), 256, 0, stream>>>(Q, K, VT, att);
    k_gemm_bt<false><<<dim3(16, 16), 256, 0, stream>>>(att, woT, d_out, 2048, 2048, 2048, 2048);
}

// Round 6
// 242.114 us; speedup vs baseline: 6.4291x; 1.1289x over previous
//
#include <hip/hip_runtime.h>
#include <hip/hip_bf16.h>
#include <cstdint>
#include <cstddef>

#define T_SEQ 2048
#define CDIM  2048
#define HQ    16
#define HKV   4
#define DHEAD 128
#define NQKV  3072   // q(2048) | k(512) | v(512)

typedef __bf16 bf8 __attribute__((ext_vector_type(8)));
typedef __bf16 bf4 __attribute__((ext_vector_type(4)));
typedef float  f4  __attribute__((ext_vector_type(4)));

static __device__ __forceinline__ f4 mfma16(bf8 a, bf8 b, f4 c) {
    return __builtin_amdgcn_mfma_f32_16x16x32_bf16(a, b, c, 0, 0, 0);
}

#define GLOAD16(g, l)                                                        \
    __builtin_amdgcn_global_load_lds(                                        \
        (const __attribute__((address_space(1))) void*)(g),                  \
        (__attribute__((address_space(3))) void*)(l), 16, 0, 0)

static __device__ __forceinline__ float toF(float v) { return v; }
static __device__ __forceinline__ float toF(__bf16 v) { return (float)v; }

// ---------------- fp32 -> bf16 elementwise (x) ----------------
__global__ __launch_bounds__(256) void k_cvt(const float* __restrict__ in,
                                             __bf16* __restrict__ out, int n4) {
    int i = blockIdx.x * 256 + threadIdx.x;
    if (i >= n4) return;
    float4 v = ((const float4*)in)[i];
    bf4 o;
    o[0] = (__bf16)v.x; o[1] = (__bf16)v.y; o[2] = (__bf16)v.z; o[3] = (__bf16)v.w;
    ((bf4*)out)[i] = o;
}

// ---------------- transpose + convert: dst[c][r] = src[r][c] ----------------
template <typename TS>
__global__ __launch_bounds__(256) void k_tpose(const TS* __restrict__ src, int ld_src,
                                               __bf16* __restrict__ dst, int ld_dst,
                                               int R, int C) {
    __shared__ float tile[32][33];
    const int c0 = blockIdx.x * 32, r0 = blockIdx.y * 32;
    const int tx = threadIdx.x, ty = threadIdx.y;
#pragma unroll
    for (int i = 0; i < 4; ++i)
        tile[ty + i * 8][tx] = toF(src[(size_t)(r0 + ty + i * 8) * ld_src + c0 + tx]);
    __syncthreads();
#pragma unroll
    for (int i = 0; i < 4; ++i)
        dst[(size_t)(c0 + ty + i * 8) * ld_dst + r0 + tx] = (__bf16)tile[tx][ty + i * 8];
}

// ---------------- RoPE cos/sin table [T][64][2] ----------------
__global__ __launch_bounds__(256) void k_rtab(float* __restrict__ tab) {
    int idx = blockIdx.x * 256 + threadIdx.x;  // T*64
    int t = idx >> 6, j = idx & 63;
    float invf = expf(-(float)j * (9.210340371976184f / 64.0f));  // 10000^(-j/64)
    float a = (float)t * invf;
    tab[idx * 2 + 0] = cosf(a);
    tab[idx * 2 + 1] = sinf(a);
}

// ---------------- RoPE apply: qkv(bf16) -> Q [H][T][D], K [HKV][T][D] ----------------
__global__ __launch_bounds__(256) void k_rope(const __bf16* __restrict__ qkv,
                                              const float* __restrict__ tab,
                                              __bf16* __restrict__ Q,
                                              __bf16* __restrict__ K) {
    int idx = blockIdx.x * 256 + threadIdx.x;  // T * 20 * 64
    int j = idx & 63;
    int hd = (idx >> 6) % 20;
    int t = idx / (20 * 64);
    const __bf16* base;
    __bf16* dst;
    if (hd < HQ) {
        base = qkv + (size_t)t * NQKV + hd * DHEAD;
        dst = Q + ((size_t)hd * T_SEQ + t) * DHEAD;
    } else {
        int kvh = hd - HQ;
        base = qkv + (size_t)t * NQKV + CDIM + kvh * DHEAD;
        dst = K + ((size_t)kvh * T_SEQ + t) * DHEAD;
    }
    float a = (float)base[j], b = (float)base[j + 64];
    float c = tab[(t * 64 + j) * 2 + 0];
    float s = tab[(t * 64 + j) * 2 + 1];
    dst[j] = (__bf16)(a * c - b * s);
    dst[j + 64] = (__bf16)(b * c + a * s);
}

// ---------------- GEMM (m97-style): C[M][N] = A[M][K] * BT[N][K]^T ----------------
template <bool OBF>
__global__ __launch_bounds__(256) void k_gemm_bt(const __bf16* __restrict__ A,
                                                 const __bf16* __restrict__ BT,
                                                 void* __restrict__ C,
                                                 int M, int N, int K, int ldc) {
    __shared__ __bf16 Al[128 * 32];  // linear, 64B rows
    __shared__ __bf16 Bl[128 * 32];
    const int tid = threadIdx.x;
    const int wid = tid >> 6, lane = tid & 63;
    const int l15 = lane & 15, lhi = lane >> 4;
    const int wr = wid >> 1, wc = wid & 1;
    const size_t arow0 = (size_t)blockIdx.y * 128;
    const size_t brow0 = (size_t)blockIdx.x * 128;

    const int srow = wid * 16 + (lane >> 2);
    const int scol = ((lane & 3) ^ ((lane >> 3) & 3)) * 8;
    const __bf16* Ag0 = A + (arow0 + srow) * K + scol;
    const __bf16* Ag1 = Ag0 + (size_t)64 * K;
    const __bf16* Bg0 = BT + (brow0 + srow) * K + scol;
    const __bf16* Bg1 = Bg0 + (size_t)64 * K;
    char* AlB = (char*)&Al[0];
    char* BlB = (char*)&Bl[0];

    f4 acc[4][4] = {};
    const int c16 = (lhi ^ ((l15 >> 1) & 3)) * 16;

    for (int k0 = 0; k0 < K; k0 += 32) {
        GLOAD16(Ag0 + k0, AlB + wid * 1024);
        GLOAD16(Ag1 + k0, AlB + 4096 + wid * 1024);
        GLOAD16(Bg0 + k0, BlB + wid * 1024);
        GLOAD16(Bg1 + k0, BlB + 4096 + wid * 1024);
        __syncthreads();
        bf8 af[4], bfr[4];
#pragma unroll
        for (int m = 0; m < 4; ++m) {
            int r = wr * 64 + m * 16 + l15;
            af[m] = *(const bf8*)(AlB + r * 64 + c16);
        }
#pragma unroll
        for (int n = 0; n < 4; ++n) {
            int r = wc * 64 + n * 16 + l15;
            bfr[n] = *(const bf8*)(BlB + r * 64 + c16);
        }
#pragma unroll
        for (int m = 0; m < 4; ++m)
#pragma unroll
            for (int n = 0; n < 4; ++n)
                acc[m][n] = mfma16(af[m], bfr[n], acc[m][n]);
        __syncthreads();
    }

    const int row0 = blockIdx.y * 128 + wr * 64, col0 = blockIdx.x * 128 + wc * 64;
#pragma unroll
    for (int m = 0; m < 4; ++m)
#pragma unroll
        for (int n = 0; n < 4; ++n)
#pragma unroll
            for (int j = 0; j < 4; ++j) {
                int r = row0 + m * 16 + lhi * 4 + j;
                int c = col0 + n * 16 + l15;
                float v = acc[m][n][j];
                if (OBF)
                    ((__bf16*)C)[(size_t)r * ldc + c] = (__bf16)v;
                else
                    ((float*)C)[(size_t)r * ldc + c] = v;
            }
}

// ---------------- dual-softmax flash attention ----------------
// grid (32,16), 256 thr (4 waves x 16 q-rows).
// qt = (head<8) ? 31-bx : bx  -> CU pairs {id,id+256} get complementary work.
// K/V double-buffered via global_load_lds (pre-swizzled source, rule #21);
// ONE barrier per tile; loads overlap full tile compute.
// Softmax/mask algebra identical to verified r5 kernel.
__global__ __launch_bounds__(256) void k_attn(const __bf16* __restrict__ Q,
                                              const __bf16* __restrict__ Kr,
                                              const __bf16* __restrict__ VT,
                                              __bf16* __restrict__ att) {
    __shared__ __bf16 Kl[2][64 * 128];   // 16KB each, 256B rows, 4-bit XOR swz
    __shared__ __bf16 Vl[2][128 * 64];   // 16KB each, 128B rows, 3-bit XOR swz
    __shared__ __bf16 Pl[4][1024];       // per-wave 2KB, 128B rows, swizzled
    __shared__ __bf16 Pw[4][1024];
    const int h = blockIdx.y, kvh = h >> 2;
    const int qt = (blockIdx.y < 8) ? (31 - (int)blockIdx.x) : (int)blockIdx.x;
    const int tid = threadIdx.x, wid = tid >> 6, lane = tid & 63;
    const int l15 = lane & 15, lhi = lane >> 4;
    const int q0w = qt * 64 + wid * 16;
    const bool hasloc = qt >= 4;                 // qt<4: local mask == causal mask
    const int lfLo = 4 * (qt >> 2) - 2;          // first window tile (qt>=4)
    const int lpart = qt - 2;                    // the single masked-local tile
    const float CE = 0.12751741f;                // (1/sqrt(128)) * log2(e)
    const float L2E = 1.44269504f;
    const float SCL = 0.08838834764831845f;
    const float THR = 5.5451774f;                // 8*ln2

    char* KlB = (char*)&Kl[0][0];
    char* VlB = (char*)&Vl[0][0];
    char* PlB = (char*)&Pl[0][0] + wid * 2048;
    char* PwB = (char*)&Pw[0][0] + wid * 2048;

    // ---- staging source addressing (inverse-swizzled, per-lane) ----
    // K issue i: lds row = wid*16 + 4i + lhi, granule = l15; content swz key = row&15
    const __bf16* KgB = Kr + (size_t)kvh * T_SEQ * DHEAD;
    // V issue i: lds row = wid*32 + 8i + (lane>>3), granule = lane&7; swz key = row&7
    const __bf16* VgB = VT + ((size_t)kvh * DHEAD + wid * 32 + (lane >> 3)) * T_SEQ +
                        (((lane & 7) ^ (lane >> 3)) << 3);
    const int krowL = wid * 16 + lhi;  // + 4*i

#define STAGE_KV(bsel, kb)                                                      \
    {                                                                           \
        _Pragma("unroll") for (int i = 0; i < 4; ++i) {                         \
            GLOAD16(KgB + (size_t)((kb) + krowL + 4 * i) * DHEAD +              \
                        ((l15 ^ (4 * i + lhi)) << 3),                           \
                    KlB + (bsel) + wid * 4096 + i * 1024);                      \
            GLOAD16(VgB + (kb) + (size_t)i * 8 * T_SEQ,                         \
                    VlB + (bsel) + wid * 4096 + i * 1024);                      \
        }                                                                       \
    }

    bf8 qf[4];
#pragma unroll
    for (int dc = 0; dc < 4; ++dc)
        qf[dc] = *(const bf8*)&Q[((size_t)h * T_SEQ + q0w + l15) * DHEAD + dc * 32 + lhi * 8];

    f4 oc[8] = {}, ow[8] = {};
    float mg[4], sgp[4], slp[4];
#pragma unroll
    for (int j = 0; j < 4; ++j) { mg[j] = -__builtin_inff(); sgp[j] = slp[j] = 0.f; }
    float mgmin = -__builtin_inff();

    // prologue: stage tile 0 into buffer 0
    STAGE_KV(0, 0);
    __syncthreads();
    int cur = 0;

    for (int kt = 0; kt <= qt; ++kt) {
        const int kb = kt * 64;
        const bool last = (kt == qt);
        if (!last) STAGE_KV((cur ^ 1) << 14, kb + 64);  // T3: loads fly over compute
        const int cb = cur << 14;

        // ---- QK^T ----
        f4 sc[4] = {};
        __builtin_amdgcn_s_setprio(1);
#pragma unroll
        for (int ks = 0; ks < 4; ++ks)
#pragma unroll
            for (int dc = 0; dc < 4; ++dc) {
                bf8 kf = *(const bf8*)(KlB + cb + (ks * 16 + l15) * 256 +
                                       (((dc * 4 + lhi) ^ l15) << 4));
                sc[ks] = mfma16(qf[dc], kf, sc[ks]);
            }
        __builtin_amdgcn_s_setprio(0);

        float t[4][4];
#pragma unroll
        for (int ks = 0; ks < 4; ++ks)
#pragma unroll
            for (int j = 0; j < 4; ++j) t[ks][j] = sc[ks][j];
        if (last) {  // causal mask (only tile that needs it)
#pragma unroll
            for (int ks = 0; ks < 4; ++ks)
#pragma unroll
                for (int j = 0; j < 4; ++j)
                    if (kb + ks * 16 + l15 > q0w + lhi * 4 + j) t[ks][j] = -3.0e38f;
        }
        // ---- single defer-max gate ----
        float mx = t[0][0];
#pragma unroll
        for (int ks = 0; ks < 4; ++ks)
#pragma unroll
            for (int j = 0; j < 4; ++j) mx = fmaxf(mx, t[ks][j]);
        mx *= SCL;
        if (!__all(mx <= mgmin + THR)) {
#pragma unroll
            for (int j = 0; j < 4; ++j) {
                float m2 = fmaxf(fmaxf(t[0][j], t[1][j]), fmaxf(t[2][j], t[3][j])) * SCL;
#pragma unroll
                for (int x = 1; x < 16; x <<= 1) m2 = fmaxf(m2, __shfl_xor(m2, x));
                float mn = fmaxf(mg[j], m2);
                float f = __builtin_amdgcn_exp2f((mg[j] - mn) * L2E);
                mg[j] = mn;
                sgp[j] *= f; slp[j] *= f;
#pragma unroll
                for (int nd = 0; nd < 8; ++nd) { oc[nd][j] *= f; ow[nd][j] *= f; }
            }
            mgmin = fminf(fminf(mg[0], mg[1]), fminf(mg[2], mg[3]));
        }
        // ---- branch-free exp ----
        float p[4][4], psum[4];
#pragma unroll
        for (int j = 0; j < 4; ++j) {
            const float bj = mg[j] * L2E;
#pragma unroll
            for (int ks = 0; ks < 4; ++ks)
                p[ks][j] = __builtin_amdgcn_exp2f(t[ks][j] * CE - bj);
            psum[j] = (p[0][j] + p[1][j]) + (p[2][j] + p[3][j]);
            sgp[j] += psum[j];
        }
        // ---- P stores (swizzled per-wave buffers) ----
        const bool part = hasloc && (kt == lpart);
        if (!part) {
#pragma unroll
            for (int j = 0; j < 4; ++j) {
                const int rsw = ((lhi * 4 + j) & 7) << 4;
                const int rb = (lhi * 4 + j) * 128;
#pragma unroll
                for (int ks = 0; ks < 4; ++ks)
                    *(__bf16*)(PlB + rb + ((ks * 32 + 2 * l15) ^ rsw)) = (__bf16)p[ks][j];
            }
        } else {
            const int e = q0w + lhi * 4 - 128 - kb - l15;  // window: ks*16 <= e+j
#pragma unroll
            for (int j = 0; j < 4; ++j) {
                const int rsw = ((lhi * 4 + j) & 7) << 4;
                const int rb = (lhi * 4 + j) * 128;
                float lsum = 0.f;
#pragma unroll
                for (int ks = 0; ks < 4; ++ks) {
                    float l = (ks * 16 <= e + j) ? p[ks][j] : 0.f;
                    lsum += l;
                    *(__bf16*)(PwB + rb + ((ks * 32 + 2 * l15) ^ rsw)) = (__bf16)l;
                    *(__bf16*)(PlB + rb + ((ks * 32 + 2 * l15) ^ rsw)) = (__bf16)(p[ks][j] - l);
                }
                slp[j] += lsum;
            }
        }
        const bool inwin = hasloc && kt >= lfLo && kt < lpart;
        if (inwin) {
#pragma unroll
            for (int j = 0; j < 4; ++j) slp[j] += psum[j];
        }
        // ---- PV ----
        const int psw = (l15 & 7) << 4;
        bf8 pf0 = *(const bf8*)(PlB + l15 * 128 + ((lhi << 4) ^ psw));
        bf8 pf1 = *(const bf8*)(PlB + l15 * 128 + ((64 + (lhi << 4)) ^ psw));
        __builtin_amdgcn_s_setprio(1);
        if (part) {
            bf8 pw0 = *(const bf8*)(PwB + l15 * 128 + ((lhi << 4) ^ psw));
            bf8 pw1 = *(const bf8*)(PwB + l15 * 128 + ((64 + (lhi << 4)) ^ psw));
#pragma unroll
            for (int nd = 0; nd < 8; ++nd) {
                bf8 v0 = *(const bf8*)(VlB + cb + (nd * 16 + l15) * 128 + ((lhi << 4) ^ psw));
                bf8 v1 = *(const bf8*)(VlB + cb + (nd * 16 + l15) * 128 + ((64 + (lhi << 4)) ^ psw));
                oc[nd] = mfma16(pf0, v0, oc[nd]);
                oc[nd] = mfma16(pf1, v1, oc[nd]);
                ow[nd] = mfma16(pw0, v0, ow[nd]);
                ow[nd] = mfma16(pw1, v1, ow[nd]);
            }
        } else if (inwin) {
#pragma unroll
            for (int nd = 0; nd < 8; ++nd) {
                bf8 v0 = *(const bf8*)(VlB + cb + (nd * 16 + l15) * 128 + ((lhi << 4) ^ psw));
                bf8 v1 = *(const bf8*)(VlB + cb + (nd * 16 + l15) * 128 + ((64 + (lhi << 4)) ^ psw));
                ow[nd] = mfma16(pf0, v0, ow[nd]);
                ow[nd] = mfma16(pf1, v1, ow[nd]);
            }
        } else {
#pragma unroll
            for (int nd = 0; nd < 8; ++nd) {
                bf8 v0 = *(const bf8*)(VlB + cb + (nd * 16 + l15) * 128 + ((lhi << 4) ^ psw));
                bf8 v1 = *(const bf8*)(VlB + cb + (nd * 16 + l15) * 128 + ((64 + (lhi << 4)) ^ psw));
                oc[nd] = mfma16(pf0, v0, oc[nd]);
                oc[nd] = mfma16(pf1, v1, oc[nd]);
            }
        }
        __builtin_amdgcn_s_setprio(0);
        __syncthreads();   // drains this tile's staging (vmcnt 0) + frees cur buffer
        cur ^= 1;
    }

    // ---- single final denominator reduction ----
#pragma unroll
    for (int j = 0; j < 4; ++j) {
#pragma unroll
        for (int x = 1; x < 16; x <<= 1) {
            sgp[j] += __shfl_xor(sgp[j], x);
            slp[j] += __shfl_xor(slp[j], x);
        }
    }
    float rg[4], rl[4];
#pragma unroll
    for (int j = 0; j < 4; ++j) {
        rg[j] = 1.f / sgp[j];
        rl[j] = hasloc ? 0.5f / slp[j] : 0.f;
    }
#pragma unroll
    for (int nd = 0; nd < 8; ++nd)
#pragma unroll
        for (int j = 0; j < 4; ++j) {
            int q = q0w + lhi * 4 + j;
            float go = oc[nd][j] + ow[nd][j];
            float v = hasloc ? (go * (0.5f * rg[j]) + ow[nd][j] * rl[j]) : go * rg[j];
            att[(size_t)q * CDIM + h * DHEAD + nd * 16 + l15] = (__bf16)v;
        }
#undef STAGE_KV
}

// ---------------- launcher ----------------
extern "C" void kernel_launch(void* const* d_in, const int* in_sizes, int n_in,
                              void* d_out, int out_size, void* d_ws, size_t ws_size,
                              hipStream_t stream) {
    const float* x  = (const float*)d_in[0];
    const float* wq = (const float*)d_in[1];
    const float* wk = (const float*)d_in[2];
    const float* wv = (const float*)d_in[3];
    const float* wo = (const float*)d_in[4];
    char* ws = (char*)d_ws;

    __bf16* xbf   = (__bf16*)(ws + 0);          // 8 MB
    __bf16* wqkvT = (__bf16*)(ws + 8388608);    // 12 MB  [3072][2048]
    __bf16* woT   = (__bf16*)(ws + 20971520);   // 8 MB   [2048][2048]
    __bf16* qkv   = (__bf16*)(ws + 29360128);   // 12 MB  [2048][3072]
    __bf16* Q     = (__bf16*)(ws + 41943040);   // 8 MB   [16][2048][128]
    __bf16* K     = (__bf16*)(ws + 50331648);   // 2 MB   [4][2048][128]
    __bf16* VT    = (__bf16*)(ws + 52428800);   // 2 MB   [4][128][2048]
    __bf16* att   = (__bf16*)(ws + 54525952);   // 8 MB   [2048][2048]
    float*  tab   = (float*)(ws + 62914560);    // 1 MB   [2048][64][2]

    k_cvt<<<4096, 256, 0, stream>>>(x, xbf, 1048576);
    k_tpose<float><<<dim3(64, 64), dim3(32, 8), 0, stream>>>(wq, 2048, wqkvT, 2048, 2048, 2048);
    k_tpose<float><<<dim3(16, 64), dim3(32, 8), 0, stream>>>(wk, 512, wqkvT + (size_t)2048 * 2048, 2048, 2048, 512);
    k_tpose<float><<<dim3(16, 64), dim3(32, 8), 0, stream>>>(wv, 512, wqkvT + (size_t)2560 * 2048, 2048, 2048, 512);
    k_tpose<float><<<dim3(64, 64), dim3(32, 8), 0, stream>>>(wo, 2048, woT, 2048, 2048, 2048);
    k_rtab<<<512, 256, 0, stream>>>(tab);
    k_gemm_bt<true><<<dim3(24, 16), 256, 0, stream>>>(xbf, wqkvT, qkv, 2048, 3072, 2048, 3072);
    k_rope<<<10240, 256, 0, stream>>>(qkv, tab, Q, K);
    k_tpose<__bf16><<<dim3(16, 64), dim3(32, 8), 0, stream>>>(qkv + 2560, 3072, VT, 2048, 2048, 512);
    k_attn<<<dim3(32, 16), 256, 0, stream>>>(Q, K, VT, att);
    k_gemm_bt<false><<<dim3(16, 16), 256, 0, stream>>>(att, woT, d_out, 2048, 2048, 2048, 2048);
}

// Round 8
// 187.216 us; speedup vs baseline: 8.3144x; 1.2932x over previous
//
#include <hip/hip_runtime.h>
#include <hip/hip_bf16.h>
#include <cstdint>
#include <cstddef>

#define T_SEQ 2048
#define CDIM  2048
#define HQ    16
#define HKV   4
#define DHEAD 128
#define NQKV  3072   // q(2048) | k(512) | v(512)

typedef __bf16 bf8 __attribute__((ext_vector_type(8)));
typedef __bf16 bf4 __attribute__((ext_vector_type(4)));
typedef float  f4  __attribute__((ext_vector_type(4)));

static __device__ __forceinline__ f4 mfma16(bf8 a, bf8 b, f4 c) {
    return __builtin_amdgcn_mfma_f32_16x16x32_bf16(a, b, c, 0, 0, 0);
}

#define GLOAD16(g, l)                                                        \
    __builtin_amdgcn_global_load_lds(                                        \
        (const __attribute__((address_space(1))) void*)(g),                  \
        (__attribute__((address_space(3))) void*)(l), 16, 0, 0)

static __device__ __forceinline__ float toF(float v) { return v; }
static __device__ __forceinline__ float toF(__bf16 v) { return (float)v; }

// ---------------- fused: fp32->bf16 convert (x) + RoPE table ----------------
__global__ __launch_bounds__(256) void k_prep(const float* __restrict__ in,
                                              __bf16* __restrict__ out,
                                              float* __restrict__ tab) {
    const int bid = blockIdx.x;
    if (bid < 4096) {
        int i = bid * 256 + threadIdx.x;
        float4 v = ((const float4*)in)[i];
        bf4 o;
        o[0] = (__bf16)v.x; o[1] = (__bf16)v.y; o[2] = (__bf16)v.z; o[3] = (__bf16)v.w;
        ((bf4*)out)[i] = o;
    } else {
        int idx = (bid - 4096) * 256 + threadIdx.x;  // T*64
        int t = idx >> 6, j = idx & 63;
        float invf = expf(-(float)j * (9.210340371976184f / 64.0f));
        float a = (float)t * invf;
        tab[idx * 2 + 0] = cosf(a);
        tab[idx * 2 + 1] = sinf(a);
    }
}

// ---------------- fused 4-matrix transpose+convert ----------------
__global__ __launch_bounds__(256) void k_tpose4(const float* __restrict__ wq,
                                                const float* __restrict__ wk,
                                                const float* __restrict__ wv,
                                                const float* __restrict__ wo,
                                                __bf16* __restrict__ wqkvT,
                                                __bf16* __restrict__ woT) {
    __shared__ float tile[32][33];
    const int bx = blockIdx.x;
    const float* src; __bf16* dst; int ld_src, cx;
    if (bx < 64)      { src = wq; dst = wqkvT;                        ld_src = 2048; cx = bx; }
    else if (bx < 80) { src = wk; dst = wqkvT + (size_t)2048 * 2048;  ld_src = 512;  cx = bx - 64; }
    else if (bx < 96) { src = wv; dst = wqkvT + (size_t)2560 * 2048;  ld_src = 512;  cx = bx - 80; }
    else              { src = wo; dst = woT;                          ld_src = 2048; cx = bx - 96; }
    const int c0 = cx * 32, r0 = blockIdx.y * 32;
    const int tx = threadIdx.x, ty = threadIdx.y;
#pragma unroll
    for (int i = 0; i < 4; ++i)
        tile[ty + i * 8][tx] = src[(size_t)(r0 + ty + i * 8) * ld_src + c0 + tx];
    __syncthreads();
#pragma unroll
    for (int i = 0; i < 4; ++i)
        dst[(size_t)(c0 + ty + i * 8) * 2048 + r0 + tx] = (__bf16)tile[tx][ty + i * 8];
}

// ---------------- transpose + convert (VT from qkv) ----------------
template <typename TS>
__global__ __launch_bounds__(256) void k_tpose(const TS* __restrict__ src, int ld_src,
                                               __bf16* __restrict__ dst, int ld_dst,
                                               int R, int C) {
    __shared__ float tile[32][33];
    const int c0 = blockIdx.x * 32, r0 = blockIdx.y * 32;
    const int tx = threadIdx.x, ty = threadIdx.y;
#pragma unroll
    for (int i = 0; i < 4; ++i)
        tile[ty + i * 8][tx] = toF(src[(size_t)(r0 + ty + i * 8) * ld_src + c0 + tx]);
    __syncthreads();
#pragma unroll
    for (int i = 0; i < 4; ++i)
        dst[(size_t)(c0 + ty + i * 8) * ld_dst + r0 + tx] = (__bf16)tile[tx][ty + i * 8];
}

// ---------------- RoPE apply: qkv(bf16) -> Q [H][T][D], K [HKV][T][D] ----------------
__global__ __launch_bounds__(256) void k_rope(const __bf16* __restrict__ qkv,
                                              const float* __restrict__ tab,
                                              __bf16* __restrict__ Q,
                                              __bf16* __restrict__ K) {
    int idx = blockIdx.x * 256 + threadIdx.x;  // T * 20 * 64
    int j = idx & 63;
    int hd = (idx >> 6) % 20;
    int t = idx / (20 * 64);
    const __bf16* base;
    __bf16* dst;
    if (hd < HQ) {
        base = qkv + (size_t)t * NQKV + hd * DHEAD;
        dst = Q + ((size_t)hd * T_SEQ + t) * DHEAD;
    } else {
        int kvh = hd - HQ;
        base = qkv + (size_t)t * NQKV + CDIM + kvh * DHEAD;
        dst = K + ((size_t)kvh * T_SEQ + t) * DHEAD;
    }
    float a = (float)base[j], b = (float)base[j + 64];
    float c = tab[(t * 64 + j) * 2 + 0];
    float s = tab[(t * 64 + j) * 2 + 1];
    dst[j] = (__bf16)(a * c - b * s);
    dst[j + 64] = (__bf16)(b * c + a * s);
}

// ---------------- GEMM (m97-style): C[M][N] = A[M][K] * BT[N][K]^T ----------------
template <bool OBF>
__global__ __launch_bounds__(256) void k_gemm_bt(const __bf16* __restrict__ A,
                                                 const __bf16* __restrict__ BT,
                                                 void* __restrict__ C,
                                                 int M, int N, int K, int ldc) {
    __shared__ __bf16 Al[128 * 32];  // linear, 64B rows
    __shared__ __bf16 Bl[128 * 32];
    const int tid = threadIdx.x;
    const int wid = tid >> 6, lane = tid & 63;
    const int l15 = lane & 15, lhi = lane >> 4;
    const int wr = wid >> 1, wc = wid & 1;
    const size_t arow0 = (size_t)blockIdx.y * 128;
    const size_t brow0 = (size_t)blockIdx.x * 128;

    const int srow = wid * 16 + (lane >> 2);
    const int scol = ((lane & 3) ^ ((lane >> 3) & 3)) * 8;
    const __bf16* Ag0 = A + (arow0 + srow) * K + scol;
    const __bf16* Ag1 = Ag0 + (size_t)64 * K;
    const __bf16* Bg0 = BT + (brow0 + srow) * K + scol;
    const __bf16* Bg1 = Bg0 + (size_t)64 * K;
    char* AlB = (char*)&Al[0];
    char* BlB = (char*)&Bl[0];

    f4 acc[4][4] = {};
    const int c16 = (lhi ^ ((l15 >> 1) & 3)) * 16;

    for (int k0 = 0; k0 < K; k0 += 32) {
        GLOAD16(Ag0 + k0, AlB + wid * 1024);
        GLOAD16(Ag1 + k0, AlB + 4096 + wid * 1024);
        GLOAD16(Bg0 + k0, BlB + wid * 1024);
        GLOAD16(Bg1 + k0, BlB + 4096 + wid * 1024);
        __syncthreads();
        bf8 af[4], bfr[4];
#pragma unroll
        for (int m = 0; m < 4; ++m) {
            int r = wr * 64 + m * 16 + l15;
            af[m] = *(const bf8*)(AlB + r * 64 + c16);
        }
#pragma unroll
        for (int n = 0; n < 4; ++n) {
            int r = wc * 64 + n * 16 + l15;
            bfr[n] = *(const bf8*)(BlB + r * 64 + c16);
        }
#pragma unroll
        for (int m = 0; m < 4; ++m)
#pragma unroll
            for (int n = 0; n < 4; ++n)
                acc[m][n] = mfma16(af[m], bfr[n], acc[m][n]);
        __syncthreads();
    }

    const int row0 = blockIdx.y * 128 + wr * 64, col0 = blockIdx.x * 128 + wc * 64;
#pragma unroll
    for (int m = 0; m < 4; ++m)
#pragma unroll
        for (int n = 0; n < 4; ++n)
#pragma unroll
            for (int j = 0; j < 4; ++j) {
                int r = row0 + m * 16 + lhi * 4 + j;
                int c = col0 + n * 16 + l15;
                float v = acc[m][n][j];
                if (OBF)
                    ((__bf16*)C)[(size_t)r * ldc + c] = (__bf16)v;
                else
                    ((float*)C)[(size_t)r * ldc + c] = v;
            }
}

// ---------------- dual-softmax flash attention, key-split across wave halves ----------------
// grid (32,16) x 512 thr (8 waves). Waves 0-3: even key tiles; 4-7: odd key tiles,
// same 64 q-rows. Per-half online softmax; exact merge at end. K/V double-buffered
// 128-key rounds via global_load_lds (pre-swizzled source). 17 rounds on every CU
// (complementary qt pair runs sequentially at 1 block/CU).
__global__ __launch_bounds__(512) void k_attn(const __bf16* __restrict__ Q,
                                              const __bf16* __restrict__ Kr,
                                              const __bf16* __restrict__ VT,
                                              __bf16* __restrict__ att) {
    __shared__ __align__(16) char lds[155648];
    char* KlB  = lds;               // [2][128 keys][256B d], 4-bit row XOR swz
    char* VlB  = lds + 65536;       // [2][128 d][256B keys], 4-bit row XOR swz
    char* PlB0 = lds + 131072;      // 8 waves x 2KB
    char* PwB0 = lds + 147456;      // 4 qw x 2KB (parity-active waves only)

    const int h = blockIdx.y, kvh = h >> 2;
    const int qt = (blockIdx.y < 8) ? (31 - (int)blockIdx.x) : (int)blockIdx.x;
    const int tid = threadIdx.x, wid = tid >> 6, lane = tid & 63;
    const int l15 = lane & 15, lhi = lane >> 4;
    const int par = wid >> 2, qw = wid & 3;
    const int q0w = qt * 64 + qw * 16;
    const bool hasloc = qt >= 4;
    const int lfLo = 4 * (qt >> 2) - 2;
    const int lpart = qt - 2;
    const float CE = 0.12751741f;                // (1/sqrt(128)) * log2(e)
    const float L2E = 1.44269504f;
    const float SCL = 0.08838834764831845f;
    const float THR = 5.5451774f;                // 8*ln2

    char* PlB = PlB0 + wid * 2048;
    char* PwB = PwB0 + qw * 2048;

    // staging addressing (inverse-swizzled source, linear LDS dest)
    const int srow = tid >> 4;                        // 0..31
    const int sg = (((tid & 15) ^ (srow & 15)) << 3); // elem offset
    const __bf16* KgB = Kr + (size_t)kvh * T_SEQ * DHEAD;
    const __bf16* VgB = VT + (size_t)kvh * DHEAD * T_SEQ;

#define STAGE(bsel, kb2)                                                          \
    {                                                                             \
        _Pragma("unroll") for (int i = 0; i < 4; ++i) {                           \
            GLOAD16(KgB + (size_t)((kb2) + i * 32 + srow) * DHEAD + sg,           \
                    KlB + (bsel) + i * 8192 + tid * 16);                          \
            GLOAD16(VgB + (size_t)(i * 32 + srow) * T_SEQ + (kb2) + sg,           \
                    VlB + (bsel) + i * 8192 + tid * 16);                          \
        }                                                                         \
    }

    bf8 qf[4];
#pragma unroll
    for (int dc = 0; dc < 4; ++dc)
        qf[dc] = *(const bf8*)&Q[((size_t)h * T_SEQ + q0w + l15) * DHEAD + dc * 32 + lhi * 8];

    f4 oc[8] = {}, ow[8] = {};
    float mg[4], sgp[4], slp[4];
#pragma unroll
    for (int j = 0; j < 4; ++j) { mg[j] = -__builtin_inff(); sgp[j] = slp[j] = 0.f; }
    float mgmin = -__builtin_inff();

    const int R = (qt >> 1) + 1;
    STAGE(0, 0);
    __syncthreads();
    int cur = 0;

    for (int r = 0; r < R; ++r) {
        if (r + 1 < R) STAGE((cur ^ 1) * 32768, (r + 1) * 128);
        const int kt = 2 * r + par;
        if (kt <= qt) {
            const int kb = kt * 64;
            const int cb = cur * 32768;
            const int rowb = par * 64;
            // ---- QK^T ----
            f4 sc[4] = {};
            __builtin_amdgcn_s_setprio(1);
#pragma unroll
            for (int ks = 0; ks < 4; ++ks)
#pragma unroll
                for (int dc = 0; dc < 4; ++dc) {
                    bf8 kf = *(const bf8*)(KlB + cb + (rowb + ks * 16 + l15) * 256 +
                                           (((dc * 4 + lhi) ^ l15) << 4));
                    sc[ks] = mfma16(qf[dc], kf, sc[ks]);
                }
            __builtin_amdgcn_s_setprio(0);

            float t[4][4];
#pragma unroll
            for (int ks = 0; ks < 4; ++ks)
#pragma unroll
                for (int j = 0; j < 4; ++j) t[ks][j] = sc[ks][j];
            if (kt == qt) {  // causal mask (last tile only)
#pragma unroll
                for (int ks = 0; ks < 4; ++ks)
#pragma unroll
                    for (int j = 0; j < 4; ++j)
                        if (kb + ks * 16 + l15 > q0w + lhi * 4 + j) t[ks][j] = -3.0e38f;
            }
            // ---- single defer-max gate ----
            float mx = t[0][0];
#pragma unroll
            for (int ks = 0; ks < 4; ++ks)
#pragma unroll
                for (int j = 0; j < 4; ++j) mx = fmaxf(mx, t[ks][j]);
            mx *= SCL;
            if (!__all(mx <= mgmin + THR)) {
#pragma unroll
                for (int j = 0; j < 4; ++j) {
                    float m2 = fmaxf(fmaxf(t[0][j], t[1][j]), fmaxf(t[2][j], t[3][j])) * SCL;
#pragma unroll
                    for (int x = 1; x < 16; x <<= 1) m2 = fmaxf(m2, __shfl_xor(m2, x));
                    float mn = fmaxf(mg[j], m2);
                    float f = __builtin_amdgcn_exp2f((mg[j] - mn) * L2E);
                    mg[j] = mn;
                    sgp[j] *= f; slp[j] *= f;
#pragma unroll
                    for (int nd = 0; nd < 8; ++nd) { oc[nd][j] *= f; ow[nd][j] *= f; }
                }
                mgmin = fminf(fminf(mg[0], mg[1]), fminf(mg[2], mg[3]));
            }
            // ---- branch-free exp ----
            float p[4][4], psum[4];
#pragma unroll
            for (int j = 0; j < 4; ++j) {
                const float bj = mg[j] * L2E;
#pragma unroll
                for (int ks = 0; ks < 4; ++ks)
                    p[ks][j] = __builtin_amdgcn_exp2f(t[ks][j] * CE - bj);
                psum[j] = (p[0][j] + p[1][j]) + (p[2][j] + p[3][j]);
                sgp[j] += psum[j];
            }
            // ---- P stores ----
            const bool part = hasloc && (kt == lpart);
            if (!part) {
#pragma unroll
                for (int j = 0; j < 4; ++j) {
                    const int rsw = ((lhi * 4 + j) & 7) << 4;
                    const int rb = (lhi * 4 + j) * 128;
#pragma unroll
                    for (int ks = 0; ks < 4; ++ks)
                        *(__bf16*)(PlB + rb + ((ks * 32 + 2 * l15) ^ rsw)) = (__bf16)p[ks][j];
                }
            } else {
                const int e = q0w + lhi * 4 - 128 - kb - l15;
#pragma unroll
                for (int j = 0; j < 4; ++j) {
                    const int rsw = ((lhi * 4 + j) & 7) << 4;
                    const int rb = (lhi * 4 + j) * 128;
                    float lsum = 0.f;
#pragma unroll
                    for (int ks = 0; ks < 4; ++ks) {
                        float l = (ks * 16 <= e + j) ? p[ks][j] : 0.f;
                        lsum += l;
                        *(__bf16*)(PwB + rb + ((ks * 32 + 2 * l15) ^ rsw)) = (__bf16)l;
                        *(__bf16*)(PlB + rb + ((ks * 32 + 2 * l15) ^ rsw)) = (__bf16)(p[ks][j] - l);
                    }
                    slp[j] += lsum;
                }
            }
            const bool inwin = hasloc && kt >= lfLo && kt < lpart;
            if (inwin) {
#pragma unroll
                for (int j = 0; j < 4; ++j) slp[j] += psum[j];
            }
            // ---- PV ----
            const int psw = (l15 & 7) << 4;
            bf8 pf0 = *(const bf8*)(PlB + l15 * 128 + ((lhi << 4) ^ psw));
            bf8 pf1 = *(const bf8*)(PlB + l15 * 128 + ((64 + (lhi << 4)) ^ psw));
            const int vg0 = ((par * 8 + lhi) ^ l15) << 4;
            const int vg1 = ((par * 8 + 4 + lhi) ^ l15) << 4;
            __builtin_amdgcn_s_setprio(1);
            if (part) {
                bf8 pw0 = *(const bf8*)(PwB + l15 * 128 + ((lhi << 4) ^ psw));
                bf8 pw1 = *(const bf8*)(PwB + l15 * 128 + ((64 + (lhi << 4)) ^ psw));
#pragma unroll
                for (int nd = 0; nd < 8; ++nd) {
                    bf8 v0 = *(const bf8*)(VlB + cb + (nd * 16 + l15) * 256 + vg0);
                    bf8 v1 = *(const bf8*)(VlB + cb + (nd * 16 + l15) * 256 + vg1);
                    oc[nd] = mfma16(pf0, v0, oc[nd]);
                    oc[nd] = mfma16(pf1, v1, oc[nd]);
                    ow[nd] = mfma16(pw0, v0, ow[nd]);
                    ow[nd] = mfma16(pw1, v1, ow[nd]);
                }
            } else if (inwin) {
#pragma unroll
                for (int nd = 0; nd < 8; ++nd) {
                    bf8 v0 = *(const bf8*)(VlB + cb + (nd * 16 + l15) * 256 + vg0);
                    bf8 v1 = *(const bf8*)(VlB + cb + (nd * 16 + l15) * 256 + vg1);
                    ow[nd] = mfma16(pf0, v0, ow[nd]);
                    ow[nd] = mfma16(pf1, v1, ow[nd]);
                }
            } else {
#pragma unroll
                for (int nd = 0; nd < 8; ++nd) {
                    bf8 v0 = *(const bf8*)(VlB + cb + (nd * 16 + l15) * 256 + vg0);
                    bf8 v1 = *(const bf8*)(VlB + cb + (nd * 16 + l15) * 256 + vg1);
                    oc[nd] = mfma16(pf0, v0, oc[nd]);
                    oc[nd] = mfma16(pf1, v1, oc[nd]);
                }
            }
            __builtin_amdgcn_s_setprio(0);
        }
        __syncthreads();   // drains staging (vmcnt 0) + frees cur buffer
        cur ^= 1;
    }

    // ---- split-softmax merge: waves 4-7 -> LDS, waves 0-3 combine ----
    if (par) {
        char* sb = lds + qw * 20480 + lane * 320;
#pragma unroll
        for (int nd = 0; nd < 8; ++nd) *(f4*)(sb + nd * 16) = oc[nd];
#pragma unroll
        for (int nd = 0; nd < 8; ++nd) *(f4*)(sb + 128 + nd * 16) = ow[nd];
        f4 a, b, c;
#pragma unroll
        for (int j = 0; j < 4; ++j) { a[j] = mg[j]; b[j] = sgp[j]; c[j] = slp[j]; }
        *(f4*)(sb + 256) = a; *(f4*)(sb + 272) = b; *(f4*)(sb + 288) = c;
    }
    __syncthreads();
    if (!par) {
        char* sb = lds + qw * 20480 + lane * 320;
        f4 mB = *(const f4*)(sb + 256);
        f4 sB = *(const f4*)(sb + 272);
        f4 lB = *(const f4*)(sb + 288);
        float fA[4], fB[4];
#pragma unroll
        for (int j = 0; j < 4; ++j) {
            float ms = fmaxf(mg[j], mB[j]);
            fA[j] = __builtin_amdgcn_exp2f((mg[j] - ms) * L2E);
            fB[j] = __builtin_amdgcn_exp2f((mB[j] - ms) * L2E);
            sgp[j] = sgp[j] * fA[j] + sB[j] * fB[j];
            slp[j] = slp[j] * fA[j] + lB[j] * fB[j];
        }
#pragma unroll
        for (int nd = 0; nd < 8; ++nd) {
            f4 ocB = *(const f4*)(sb + nd * 16);
            f4 owB = *(const f4*)(sb + 128 + nd * 16);
#pragma unroll
            for (int j = 0; j < 4; ++j) {
                oc[nd][j] = oc[nd][j] * fA[j] + ocB[j] * fB[j];
                ow[nd][j] = ow[nd][j] * fA[j] + owB[j] * fB[j];
            }
        }
#pragma unroll
        for (int j = 0; j < 4; ++j) {
#pragma unroll
            for (int x = 1; x < 16; x <<= 1) {
                sgp[j] += __shfl_xor(sgp[j], x);
                slp[j] += __shfl_xor(slp[j], x);
            }
        }
        float rg[4], rl[4];
#pragma unroll
        for (int j = 0; j < 4; ++j) {
            rg[j] = 1.f / sgp[j];
            rl[j] = hasloc ? 0.5f / slp[j] : 0.f;
        }
#pragma unroll
        for (int nd = 0; nd < 8; ++nd)
#pragma unroll
            for (int j = 0; j < 4; ++j) {
                int q = q0w + lhi * 4 + j;
                float go = oc[nd][j] + ow[nd][j];
                float v = hasloc ? (go * (0.5f * rg[j]) + ow[nd][j] * rl[j]) : go * rg[j];
                att[(size_t)q * CDIM + h * DHEAD + nd * 16 + l15] = (__bf16)v;
            }
    }
#undef STAGE
}

// ---------------- launcher ----------------
extern "C" void kernel_launch(void* const* d_in, const int* in_sizes, int n_in,
                              void* d_out, int out_size, void* d_ws, size_t ws_size,
                              hipStream_t stream) {
    const float* x  = (const float*)d_in[0];
    const float* wq = (const float*)d_in[1];
    const float* wk = (const float*)d_in[2];
    const float* wv = (const float*)d_in[3];
    const float* wo = (const float*)d_in[4];
    char* ws = (char*)d_ws;

    __bf16* xbf   = (__bf16*)(ws + 0);          // 8 MB
    __bf16* wqkvT = (__bf16*)(ws + 8388608);    // 12 MB  [3072][2048]
    __bf16* woT   = (__bf16*)(ws + 20971520);   // 8 MB   [2048][2048]
    __bf16* qkv   = (__bf16*)(ws + 29360128);   // 12 MB  [2048][3072]
    __bf16* Q     = (__bf16*)(ws + 41943040);   // 8 MB   [16][2048][128]
    __bf16* K     = (__bf16*)(ws + 50331648);   // 2 MB   [4][2048][128]
    __bf16* VTb   = (__bf16*)(ws + 52428800);   // 2 MB   [4][128][2048]
    __bf16* att   = (__bf16*)(ws + 54525952);   // 8 MB   [2048][2048]
    float*  tab   = (float*)(ws + 62914560);    // 1 MB   [2048][64][2]

    k_prep<<<4608, 256, 0, stream>>>(x, xbf, tab);
    k_tpose4<<<dim3(160, 64), dim3(32, 8), 0, stream>>>(wq, wk, wv, wo, wqkvT, woT);
    k_gemm_bt<true><<<dim3(24, 16), 256, 0, stream>>>(xbf, wqkvT, qkv, 2048, 3072, 2048, 3072);
    k_rope<<<10240, 256, 0, stream>>>(qkv, tab, Q, K);
    k_tpose<__bf16><<<dim3(16, 64), dim3(32, 8), 0, stream>>>(qkv + 2560, 3072, VTb, 2048, 2048, 512);
    k_attn<<<dim3(32, 16), 512, 0, stream>>>(Q, K, VTb, att);
    k_gemm_bt<false><<<dim3(16, 16), 256, 0, stream>>>(att, woT, d_out, 2048, 2048, 2048, 2048);
}

// Round 9
// 140.204 us; speedup vs baseline: 11.1023x; 1.3353x over previous
//
#include <hip/hip_runtime.h>
#include <hip/hip_bf16.h>
#include <cstdint>
#include <cstddef>

#define T_SEQ 2048
#define CDIM  2048
#define HQ    16
#define HKV   4
#define DHEAD 128
#define NQKV  3072   // q(2048) | k(512) | v(512)

typedef __bf16 bf8 __attribute__((ext_vector_type(8)));
typedef __bf16 bf4 __attribute__((ext_vector_type(4)));
typedef float  f4  __attribute__((ext_vector_type(4)));

static __device__ __forceinline__ f4 mfma16(bf8 a, bf8 b, f4 c) {
    return __builtin_amdgcn_mfma_f32_16x16x32_bf16(a, b, c, 0, 0, 0);
}

#define GLOAD16(g, l)                                                        \
    __builtin_amdgcn_global_load_lds(                                        \
        (const __attribute__((address_space(1))) void*)(g),                  \
        (__attribute__((address_space(3))) void*)(l), 16, 0, 0)

// ---------------- fused: fp32->bf16 convert (x) + RoPE table ----------------
__global__ __launch_bounds__(256) void k_prep(const float* __restrict__ in,
                                              __bf16* __restrict__ out,
                                              float* __restrict__ tab) {
    const int bid = blockIdx.x;
    if (bid < 4096) {
        int i = bid * 256 + threadIdx.x;
        float4 v = ((const float4*)in)[i];
        bf4 o;
        o[0] = (__bf16)v.x; o[1] = (__bf16)v.y; o[2] = (__bf16)v.z; o[3] = (__bf16)v.w;
        ((bf4*)out)[i] = o;
    } else {
        int idx = (bid - 4096) * 256 + threadIdx.x;  // T*64
        int t = idx >> 6, j = idx & 63;
        float invf = expf(-(float)j * (9.210340371976184f / 64.0f));
        float a = (float)t * invf;
        tab[idx * 2 + 0] = cosf(a);
        tab[idx * 2 + 1] = sinf(a);
    }
}

// ---------------- fused 4-matrix transpose+convert ----------------
__global__ __launch_bounds__(256) void k_tpose4(const float* __restrict__ wq,
                                                const float* __restrict__ wk,
                                                const float* __restrict__ wv,
                                                const float* __restrict__ wo,
                                                __bf16* __restrict__ wqkvT,
                                                __bf16* __restrict__ woT) {
    __shared__ float tile[32][33];
    const int bx = blockIdx.x;
    const float* src; __bf16* dst; int ld_src, cx;
    if (bx < 64)      { src = wq; dst = wqkvT;                        ld_src = 2048; cx = bx; }
    else if (bx < 80) { src = wk; dst = wqkvT + (size_t)2048 * 2048;  ld_src = 512;  cx = bx - 64; }
    else if (bx < 96) { src = wv; dst = wqkvT + (size_t)2560 * 2048;  ld_src = 512;  cx = bx - 80; }
    else              { src = wo; dst = woT;                          ld_src = 2048; cx = bx - 96; }
    const int c0 = cx * 32, r0 = blockIdx.y * 32;
    const int tx = threadIdx.x, ty = threadIdx.y;
#pragma unroll
    for (int i = 0; i < 4; ++i)
        tile[ty + i * 8][tx] = src[(size_t)(r0 + ty + i * 8) * ld_src + c0 + tx];
    __syncthreads();
#pragma unroll
    for (int i = 0; i < 4; ++i)
        dst[(size_t)(c0 + ty + i * 8) * 2048 + r0 + tx] = (__bf16)tile[tx][ty + i * 8];
}

// ---------------- GEMM: C[M][N] = A[M][K] * BT[N][K]^T ----------------
// BK=64, double-buffered global_load_lds (T3 2-phase: stage next before compute),
// one barrier per K-step. XOR-swizzled LDS (pre-swizzled source, rule #21).
// MODE 0: fp32 C out. MODE 1: QKV fused epilogue -> RoPE'd Q/K + transposed VT.
template <int MODE>
__global__ __launch_bounds__(256, 2) void k_gemm(const __bf16* __restrict__ A,
                                                 const __bf16* __restrict__ BT,
                                                 float* __restrict__ C,
                                                 const float2* __restrict__ tab,
                                                 __bf16* __restrict__ Qo,
                                                 __bf16* __restrict__ Ko,
                                                 __bf16* __restrict__ Vo,
                                                 int M, int N, int K) {
    __shared__ __bf16 lds[2][2][128 * 64];   // [buf][mat][row*64], rows 128B
    char* L = (char*)&lds[0][0][0];
    const int tid = threadIdx.x, wid = tid >> 6, lane = tid & 63;
    const int l15 = lane & 15, lhi = lane >> 4;
    const int wr = wid >> 1, wc = wid & 1;
    const size_t arow0 = (size_t)blockIdx.y * 128;
    const size_t brow0 = (size_t)blockIdx.x * 128;

    // staging: thread tid, issue i -> lds row i*32 + tid/8, chunk tid%8;
    // content chunk = (tid%8) ^ ((tid/8)&7)  (row&7 == (tid/8)&7)
    const int sr = tid >> 3;
    const int sc8 = ((tid & 7) ^ ((tid >> 3) & 7)) * 8;
    const __bf16* Ag = A + (arow0 + sr) * K + sc8;
    const __bf16* Bg = BT + (brow0 + sr) * K + sc8;

#define GSTAGE(buf, k0)                                                          \
    {                                                                            \
        _Pragma("unroll") for (int i = 0; i < 4; ++i) {                          \
            GLOAD16(Ag + (k0) + (size_t)i * 32 * K,                              \
                    L + (buf) * 32768 + i * 4096 + tid * 16);                    \
            GLOAD16(Bg + (k0) + (size_t)i * 32 * K,                              \
                    L + (buf) * 32768 + 16384 + i * 4096 + tid * 16);            \
        }                                                                        \
    }

    f4 acc[4][4] = {};
    GSTAGE(0, 0);
    __syncthreads();
    int cur = 0;

    for (int k0 = 0; k0 < K; k0 += 64) {
        if (k0 + 64 < K) GSTAGE(cur ^ 1, k0 + 64);
        const char* Ab = L + cur * 32768;
        const char* Bb = Ab + 16384;
        bf8 af[2][4], bfr[2][4];
#pragma unroll
        for (int kk = 0; kk < 2; ++kk) {
            const int ch = ((kk * 4 + lhi) ^ (l15 & 7)) * 16;
#pragma unroll
            for (int m = 0; m < 4; ++m)
                af[kk][m] = *(const bf8*)(Ab + (wr * 64 + m * 16 + l15) * 128 + ch);
#pragma unroll
            for (int n = 0; n < 4; ++n)
                bfr[kk][n] = *(const bf8*)(Bb + (n * 32 + wc * 16 + l15) * 128 + ch);
        }
        __builtin_amdgcn_s_setprio(1);
#pragma unroll
        for (int kk = 0; kk < 2; ++kk)
#pragma unroll
            for (int m = 0; m < 4; ++m)
#pragma unroll
                for (int n = 0; n < 4; ++n)
                    acc[m][n] = mfma16(af[kk][m], bfr[kk][n], acc[m][n]);
        __builtin_amdgcn_s_setprio(0);
        __syncthreads();
        cur ^= 1;
    }
#undef GSTAGE

    const int row0 = blockIdx.y * 128 + wr * 64;
    if (MODE == 0) {
#pragma unroll
        for (int m = 0; m < 4; ++m)
#pragma unroll
            for (int n = 0; n < 4; ++n) {
                const int c = blockIdx.x * 128 + n * 32 + wc * 16 + l15;
#pragma unroll
                for (int j = 0; j < 4; ++j)
                    C[(size_t)(row0 + m * 16 + lhi * 4 + j) * N + c] = acc[m][n][j];
            }
    } else {
        const int bx = blockIdx.x;
        if (bx < 20) {
            // RoPE on fp32 acc: pair (n, n+2) = (d, d+64), d = n*32+wc*16+l15
            __bf16* dst0 = (bx < 16) ? (Qo + (size_t)bx * T_SEQ * DHEAD)
                                     : (Ko + (size_t)(bx - 16) * T_SEQ * DHEAD);
#pragma unroll
            for (int m = 0; m < 4; ++m)
#pragma unroll
                for (int n = 0; n < 2; ++n) {
                    const int d = n * 32 + wc * 16 + l15;
#pragma unroll
                    for (int j = 0; j < 4; ++j) {
                        const int t = row0 + m * 16 + lhi * 4 + j;
                        const float2 cs = tab[t * 64 + d];
                        const float a = acc[m][n][j], b = acc[m][n + 2][j];
                        dst0[(size_t)t * DHEAD + d]      = (__bf16)(a * cs.x - b * cs.y);
                        dst0[(size_t)t * DHEAD + d + 64] = (__bf16)(b * cs.x + a * cs.y);
                    }
                }
        } else {
            // V: write transposed VT[kvh][d][t], 4 consecutive t per lane
            __bf16* vdst = Vo + (size_t)(bx - 20) * DHEAD * T_SEQ;
#pragma unroll
            for (int m = 0; m < 4; ++m)
#pragma unroll
                for (int n = 0; n < 4; ++n) {
                    const int c = n * 32 + wc * 16 + l15;
                    bf4 o;
#pragma unroll
                    for (int j = 0; j < 4; ++j) o[j] = (__bf16)acc[m][n][j];
                    *(bf4*)&vdst[(size_t)c * T_SEQ + row0 + m * 16 + lhi * 4] = o;
                }
        }
    }
}

// ---------------- dual-softmax flash attention, key-split across wave halves ----------------
// grid (32,16) x 512 thr (8 waves). Waves 0-3: even key tiles; 4-7: odd key tiles,
// same 64 q-rows. Per-half online softmax; exact merge at end. K/V double-buffered
// 128-key rounds via global_load_lds (pre-swizzled source).
__global__ __launch_bounds__(512) void k_attn(const __bf16* __restrict__ Q,
                                              const __bf16* __restrict__ Kr,
                                              const __bf16* __restrict__ VT,
                                              __bf16* __restrict__ att) {
    __shared__ __align__(16) char lds[155648];
    char* KlB  = lds;               // [2][128 keys][256B d], 4-bit row XOR swz
    char* VlB  = lds + 65536;       // [2][128 d][256B keys], 4-bit row XOR swz
    char* PlB0 = lds + 131072;      // 8 waves x 2KB
    char* PwB0 = lds + 147456;      // 4 qw x 2KB (parity-active waves only)

    const int h = blockIdx.y, kvh = h >> 2;
    const int qt = (blockIdx.y < 8) ? (31 - (int)blockIdx.x) : (int)blockIdx.x;
    const int tid = threadIdx.x, wid = tid >> 6, lane = tid & 63;
    const int l15 = lane & 15, lhi = lane >> 4;
    const int par = wid >> 2, qw = wid & 3;
    const int q0w = qt * 64 + qw * 16;
    const bool hasloc = qt >= 4;
    const int lfLo = 4 * (qt >> 2) - 2;
    const int lpart = qt - 2;
    const float CE = 0.12751741f;                // (1/sqrt(128)) * log2(e)
    const float L2E = 1.44269504f;
    const float SCL = 0.08838834764831845f;
    const float THR = 5.5451774f;                // 8*ln2

    char* PlB = PlB0 + wid * 2048;
    char* PwB = PwB0 + qw * 2048;

    const int srow = tid >> 4;                        // 0..31
    const int sg = (((tid & 15) ^ (srow & 15)) << 3); // elem offset
    const __bf16* KgB = Kr + (size_t)kvh * T_SEQ * DHEAD;
    const __bf16* VgB = VT + (size_t)kvh * DHEAD * T_SEQ;

#define STAGE(bsel, kb2)                                                          \
    {                                                                             \
        _Pragma("unroll") for (int i = 0; i < 4; ++i) {                           \
            GLOAD16(KgB + (size_t)((kb2) + i * 32 + srow) * DHEAD + sg,           \
                    KlB + (bsel) + i * 8192 + tid * 16);                          \
            GLOAD16(VgB + (size_t)(i * 32 + srow) * T_SEQ + (kb2) + sg,           \
                    VlB + (bsel) + i * 8192 + tid * 16);                          \
        }                                                                         \
    }

    bf8 qf[4];
#pragma unroll
    for (int dc = 0; dc < 4; ++dc)
        qf[dc] = *(const bf8*)&Q[((size_t)h * T_SEQ + q0w + l15) * DHEAD + dc * 32 + lhi * 8];

    f4 oc[8] = {}, ow[8] = {};
    float mg[4], sgp[4], slp[4];
#pragma unroll
    for (int j = 0; j < 4; ++j) { mg[j] = -__builtin_inff(); sgp[j] = slp[j] = 0.f; }
    float mgmin = -__builtin_inff();

    const int R = (qt >> 1) + 1;
    STAGE(0, 0);
    __syncthreads();
    int cur = 0;

    for (int r = 0; r < R; ++r) {
        if (r + 1 < R) STAGE((cur ^ 1) * 32768, (r + 1) * 128);
        const int kt = 2 * r + par;
        if (kt <= qt) {
            const int kb = kt * 64;
            const int cb = cur * 32768;
            const int rowb = par * 64;
            // ---- QK^T ----
            f4 sc[4] = {};
            __builtin_amdgcn_s_setprio(1);
#pragma unroll
            for (int ks = 0; ks < 4; ++ks)
#pragma unroll
                for (int dc = 0; dc < 4; ++dc) {
                    bf8 kf = *(const bf8*)(KlB + cb + (rowb + ks * 16 + l15) * 256 +
                                           (((dc * 4 + lhi) ^ l15) << 4));
                    sc[ks] = mfma16(qf[dc], kf, sc[ks]);
                }
            __builtin_amdgcn_s_setprio(0);

            float t[4][4];
#pragma unroll
            for (int ks = 0; ks < 4; ++ks)
#pragma unroll
                for (int j = 0; j < 4; ++j) t[ks][j] = sc[ks][j];
            if (kt == qt) {  // causal mask (last tile only)
#pragma unroll
                for (int ks = 0; ks < 4; ++ks)
#pragma unroll
                    for (int j = 0; j < 4; ++j)
                        if (kb + ks * 16 + l15 > q0w + lhi * 4 + j) t[ks][j] = -3.0e38f;
            }
            // ---- single defer-max gate ----
            float mx = t[0][0];
#pragma unroll
            for (int ks = 0; ks < 4; ++ks)
#pragma unroll
                for (int j = 0; j < 4; ++j) mx = fmaxf(mx, t[ks][j]);
            mx *= SCL;
            if (!__all(mx <= mgmin + THR)) {
#pragma unroll
                for (int j = 0; j < 4; ++j) {
                    float m2 = fmaxf(fmaxf(t[0][j], t[1][j]), fmaxf(t[2][j], t[3][j])) * SCL;
#pragma unroll
                    for (int x = 1; x < 16; x <<= 1) m2 = fmaxf(m2, __shfl_xor(m2, x));
                    float mn = fmaxf(mg[j], m2);
                    float f = __builtin_amdgcn_exp2f((mg[j] - mn) * L2E);
                    mg[j] = mn;
                    sgp[j] *= f; slp[j] *= f;
#pragma unroll
                    for (int nd = 0; nd < 8; ++nd) { oc[nd][j] *= f; ow[nd][j] *= f; }
                }
                mgmin = fminf(fminf(mg[0], mg[1]), fminf(mg[2], mg[3]));
            }
            // ---- branch-free exp ----
            float p[4][4], psum[4];
#pragma unroll
            for (int j = 0; j < 4; ++j) {
                const float bj = mg[j] * L2E;
#pragma unroll
                for (int ks = 0; ks < 4; ++ks)
                    p[ks][j] = __builtin_amdgcn_exp2f(t[ks][j] * CE - bj);
                psum[j] = (p[0][j] + p[1][j]) + (p[2][j] + p[3][j]);
                sgp[j] += psum[j];
            }
            // ---- P stores ----
            const bool part = hasloc && (kt == lpart);
            if (!part) {
#pragma unroll
                for (int j = 0; j < 4; ++j) {
                    const int rsw = ((lhi * 4 + j) & 7) << 4;
                    const int rb = (lhi * 4 + j) * 128;
#pragma unroll
                    for (int ks = 0; ks < 4; ++ks)
                        *(__bf16*)(PlB + rb + ((ks * 32 + 2 * l15) ^ rsw)) = (__bf16)p[ks][j];
                }
            } else {
                const int e = q0w + lhi * 4 - 128 - kb - l15;
#pragma unroll
                for (int j = 0; j < 4; ++j) {
                    const int rsw = ((lhi * 4 + j) & 7) << 4;
                    const int rb = (lhi * 4 + j) * 128;
                    float lsum = 0.f;
#pragma unroll
                    for (int ks = 0; ks < 4; ++ks) {
                        float l = (ks * 16 <= e + j) ? p[ks][j] : 0.f;
                        lsum += l;
                        *(__bf16*)(PwB + rb + ((ks * 32 + 2 * l15) ^ rsw)) = (__bf16)l;
                        *(__bf16*)(PlB + rb + ((ks * 32 + 2 * l15) ^ rsw)) = (__bf16)(p[ks][j] - l);
                    }
                    slp[j] += lsum;
                }
            }
            const bool inwin = hasloc && kt >= lfLo && kt < lpart;
            if (inwin) {
#pragma unroll
                for (int j = 0; j < 4; ++j) slp[j] += psum[j];
            }
            // ---- PV ----
            const int psw = (l15 & 7) << 4;
            bf8 pf0 = *(const bf8*)(PlB + l15 * 128 + ((lhi << 4) ^ psw));
            bf8 pf1 = *(const bf8*)(PlB + l15 * 128 + ((64 + (lhi << 4)) ^ psw));
            const int vg0 = ((par * 8 + lhi) ^ l15) << 4;
            const int vg1 = ((par * 8 + 4 + lhi) ^ l15) << 4;
            __builtin_amdgcn_s_setprio(1);
            if (part) {
                bf8 pw0 = *(const bf8*)(PwB + l15 * 128 + ((lhi << 4) ^ psw));
                bf8 pw1 = *(const bf8*)(PwB + l15 * 128 + ((64 + (lhi << 4)) ^ psw));
#pragma unroll
                for (int nd = 0; nd < 8; ++nd) {
                    bf8 v0 = *(const bf8*)(VlB + cb + (nd * 16 + l15) * 256 + vg0);
                    bf8 v1 = *(const bf8*)(VlB + cb + (nd * 16 + l15) * 256 + vg1);
                    oc[nd] = mfma16(pf0, v0, oc[nd]);
                    oc[nd] = mfma16(pf1, v1, oc[nd]);
                    ow[nd] = mfma16(pw0, v0, ow[nd]);
                    ow[nd] = mfma16(pw1, v1, ow[nd]);
                }
            } else if (inwin) {
#pragma unroll
                for (int nd = 0; nd < 8; ++nd) {
                    bf8 v0 = *(const bf8*)(VlB + cb + (nd * 16 + l15) * 256 + vg0);
                    bf8 v1 = *(const bf8*)(VlB + cb + (nd * 16 + l15) * 256 + vg1);
                    ow[nd] = mfma16(pf0, v0, ow[nd]);
                    ow[nd] = mfma16(pf1, v1, ow[nd]);
                }
            } else {
#pragma unroll
                for (int nd = 0; nd < 8; ++nd) {
                    bf8 v0 = *(const bf8*)(VlB + cb + (nd * 16 + l15) * 256 + vg0);
                    bf8 v1 = *(const bf8*)(VlB + cb + (nd * 16 + l15) * 256 + vg1);
                    oc[nd] = mfma16(pf0, v0, oc[nd]);
                    oc[nd] = mfma16(pf1, v1, oc[nd]);
                }
            }
            __builtin_amdgcn_s_setprio(0);
        }
        __syncthreads();   // drains staging (vmcnt 0) + frees cur buffer
        cur ^= 1;
    }

    // ---- split-softmax merge: waves 4-7 -> LDS, waves 0-3 combine ----
    if (par) {
        char* sb = lds + qw * 20480 + lane * 320;
#pragma unroll
        for (int nd = 0; nd < 8; ++nd) *(f4*)(sb + nd * 16) = oc[nd];
#pragma unroll
        for (int nd = 0; nd < 8; ++nd) *(f4*)(sb + 128 + nd * 16) = ow[nd];
        f4 a, b, c;
#pragma unroll
        for (int j = 0; j < 4; ++j) { a[j] = mg[j]; b[j] = sgp[j]; c[j] = slp[j]; }
        *(f4*)(sb + 256) = a; *(f4*)(sb + 272) = b; *(f4*)(sb + 288) = c;
    }
    __syncthreads();
    if (!par) {
        char* sb = lds + qw * 20480 + lane * 320;
        f4 mB = *(const f4*)(sb + 256);
        f4 sB = *(const f4*)(sb + 272);
        f4 lB = *(const f4*)(sb + 288);
        float fA[4], fB[4];
#pragma unroll
        for (int j = 0; j < 4; ++j) {
            float ms = fmaxf(mg[j], mB[j]);
            fA[j] = __builtin_amdgcn_exp2f((mg[j] - ms) * L2E);
            fB[j] = __builtin_amdgcn_exp2f((mB[j] - ms) * L2E);
            sgp[j] = sgp[j] * fA[j] + sB[j] * fB[j];
            slp[j] = slp[j] * fA[j] + lB[j] * fB[j];
        }
#pragma unroll
        for (int nd = 0; nd < 8; ++nd) {
            f4 ocB = *(const f4*)(sb + nd * 16);
            f4 owB = *(const f4*)(sb + 128 + nd * 16);
#pragma unroll
            for (int j = 0; j < 4; ++j) {
                oc[nd][j] = oc[nd][j] * fA[j] + ocB[j] * fB[j];
                ow[nd][j] = ow[nd][j] * fA[j] + owB[j] * fB[j];
            }
        }
#pragma unroll
        for (int j = 0; j < 4; ++j) {
#pragma unroll
            for (int x = 1; x < 16; x <<= 1) {
                sgp[j] += __shfl_xor(sgp[j], x);
                slp[j] += __shfl_xor(slp[j], x);
            }
        }
        float rg[4], rl[4];
#pragma unroll
        for (int j = 0; j < 4; ++j) {
            rg[j] = 1.f / sgp[j];
            rl[j] = hasloc ? 0.5f / slp[j] : 0.f;
        }
#pragma unroll
        for (int nd = 0; nd < 8; ++nd)
#pragma unroll
            for (int j = 0; j < 4; ++j) {
                int q = q0w + lhi * 4 + j;
                float go = oc[nd][j] + ow[nd][j];
                float v = hasloc ? (go * (0.5f * rg[j]) + ow[nd][j] * rl[j]) : go * rg[j];
                att[(size_t)q * CDIM + h * DHEAD + nd * 16 + l15] = (__bf16)v;
            }
    }
#undef STAGE
}

// ---------------- launcher ----------------
extern "C" void kernel_launch(void* const* d_in, const int* in_sizes, int n_in,
                              void* d_out, int out_size, void* d_ws, size_t ws_size,
                              hipStream_t stream) {
    const float* x  = (const float*)d_in[0];
    const float* wq = (const float*)d_in[1];
    const float* wk = (const float*)d_in[2];
    const float* wv = (const float*)d_in[3];
    const float* wo = (const float*)d_in[4];
    char* ws = (char*)d_ws;

    __bf16* xbf   = (__bf16*)(ws + 0);          // 8 MB
    __bf16* wqkvT = (__bf16*)(ws + 8388608);    // 12 MB  [3072][2048]
    __bf16* woT   = (__bf16*)(ws + 20971520);   // 8 MB   [2048][2048]
    __bf16* Q     = (__bf16*)(ws + 41943040);   // 8 MB   [16][2048][128]
    __bf16* K     = (__bf16*)(ws + 50331648);   // 2 MB   [4][2048][128]
    __bf16* VTb   = (__bf16*)(ws + 52428800);   // 2 MB   [4][128][2048]
    __bf16* att   = (__bf16*)(ws + 54525952);   // 8 MB   [2048][2048]
    float*  tab   = (float*)(ws + 62914560);    // 1 MB   [2048][64][2]

    k_prep<<<4608, 256, 0, stream>>>(x, xbf, tab);
    k_tpose4<<<dim3(160, 64), dim3(32, 8), 0, stream>>>(wq, wk, wv, wo, wqkvT, woT);
    k_gemm<1><<<dim3(24, 16), 256, 0, stream>>>(xbf, wqkvT, nullptr, (const float2*)tab,
                                                Q, K, VTb, 2048, 3072, 2048);
    k_attn<<<dim3(32, 16), 512, 0, stream>>>(Q, K, VTb, att);
    k_gemm<0><<<dim3(16, 16), 256, 0, stream>>>(att, woT, (float*)d_out, nullptr,
                                                nullptr, nullptr, nullptr, 2048, 2048, 2048);
}

// Round 10
// 138.219 us; speedup vs baseline: 11.2617x; 1.0144x over previous
//
#include <hip/hip_runtime.h>
#include <hip/hip_bf16.h>
#include <cstdint>
#include <cstddef>

#define T_SEQ 2048
#define CDIM  2048
#define HQ    16
#define HKV   4
#define DHEAD 128
#define NQKV  3072   // q(2048) | k(512) | v(512)

typedef __bf16 bf8 __attribute__((ext_vector_type(8)));
typedef __bf16 bf4 __attribute__((ext_vector_type(4)));
typedef float  f4  __attribute__((ext_vector_type(4)));

static __device__ __forceinline__ f4 mfma16(bf8 a, bf8 b, f4 c) {
    return __builtin_amdgcn_mfma_f32_16x16x32_bf16(a, b, c, 0, 0, 0);
}

#define GLOAD16(g, l)                                                        \
    __builtin_amdgcn_global_load_lds(                                        \
        (const __attribute__((address_space(1))) void*)(g),                  \
        (__attribute__((address_space(3))) void*)(l), 16, 0, 0)

// ---------------- fused prep: x->bf16, RoPE table, 4 weight transposes ----------------
__global__ __launch_bounds__(256) void k_pre(const float* __restrict__ x,
                                             const float* __restrict__ wq,
                                             const float* __restrict__ wk,
                                             const float* __restrict__ wv,
                                             const float* __restrict__ wo,
                                             __bf16* __restrict__ xbf,
                                             float* __restrict__ tab,
                                             __bf16* __restrict__ wqkvT,
                                             __bf16* __restrict__ woT) {
    const int bid = blockIdx.x, tid = threadIdx.x;
    if (bid < 4096) {
        int i = bid * 256 + tid;
        float4 v = ((const float4*)x)[i];
        bf4 o;
        o[0] = (__bf16)v.x; o[1] = (__bf16)v.y; o[2] = (__bf16)v.z; o[3] = (__bf16)v.w;
        ((bf4*)xbf)[i] = o;
        return;
    }
    if (bid < 4608) {
        int idx = (bid - 4096) * 256 + tid;  // T*64
        int t = idx >> 6, j = idx & 63;
        float invf = expf(-(float)j * (9.210340371976184f / 64.0f));
        float a = (float)t * invf;
        tab[idx * 2 + 0] = cosf(a);
        tab[idx * 2 + 1] = sinf(a);
        return;
    }
    __shared__ float tile[32][33];
    const int n = bid - 4608;
    const int bx = n % 160, by = n / 160;
    const float* src; __bf16* dst; int ld_src, cx;
    if (bx < 64)      { src = wq; dst = wqkvT;                        ld_src = 2048; cx = bx; }
    else if (bx < 80) { src = wk; dst = wqkvT + (size_t)2048 * 2048;  ld_src = 512;  cx = bx - 64; }
    else if (bx < 96) { src = wv; dst = wqkvT + (size_t)2560 * 2048;  ld_src = 512;  cx = bx - 80; }
    else              { src = wo; dst = woT;                          ld_src = 2048; cx = bx - 96; }
    const int c0 = cx * 32, r0 = by * 32;
    const int tx = tid & 31, ty = tid >> 5;
#pragma unroll
    for (int i = 0; i < 4; ++i)
        tile[ty + i * 8][tx] = src[(size_t)(r0 + ty + i * 8) * ld_src + c0 + tx];
    __syncthreads();
#pragma unroll
    for (int i = 0; i < 4; ++i)
        dst[(size_t)(c0 + ty + i * 8) * 2048 + r0 + tx] = (__bf16)tile[tx][ty + i * 8];
}

// ---------------- GEMM: C[M][N] = A[M][K] * BT[N][K]^T ----------------
// 512 thr / 8 waves (4 row x 2 col), per-wave acc[2][4] (32x128 output).
// BK=64 double-buffered global_load_lds, one barrier per K-step, XOR-swizzled LDS.
// MODE 0: fp32 C out. MODE 1: QKV fused epilogue -> RoPE'd Q/K + transposed VT.
template <int MODE>
__global__ __launch_bounds__(512, 4) void k_gemm(const __bf16* __restrict__ A,
                                                 const __bf16* __restrict__ BT,
                                                 float* __restrict__ C,
                                                 const float2* __restrict__ tab,
                                                 __bf16* __restrict__ Qo,
                                                 __bf16* __restrict__ Ko,
                                                 __bf16* __restrict__ Vo,
                                                 int M, int N, int K) {
    __shared__ __bf16 lds[2][2][128 * 64];   // [buf][mat][row*64], rows 128B
    char* L = (char*)&lds[0][0][0];
    const int tid = threadIdx.x, wid = tid >> 6, lane = tid & 63;
    const int l15 = lane & 15, lhi = lane >> 4;
    const int wr = wid >> 1, wc = wid & 1;
    const size_t arow0 = (size_t)blockIdx.y * 128;
    const size_t brow0 = (size_t)blockIdx.x * 128;

    // staging: thread tid -> lds row i*64 + tid/8, chunk tid%8;
    // content chunk = (tid%8) ^ ((tid/8)&7)  (row&7 == (tid/8)&7)
    const int sr = tid >> 3;
    const int sc8 = ((tid & 7) ^ ((tid >> 3) & 7)) * 8;
    const __bf16* Ag = A + (arow0 + sr) * K + sc8;
    const __bf16* Bg = BT + (brow0 + sr) * K + sc8;

#define GSTAGE(buf, k0)                                                          \
    {                                                                            \
        _Pragma("unroll") for (int i = 0; i < 2; ++i) {                          \
            GLOAD16(Ag + (k0) + (size_t)i * 64 * K,                              \
                    L + (buf) * 32768 + i * 8192 + tid * 16);                    \
            GLOAD16(Bg + (k0) + (size_t)i * 64 * K,                              \
                    L + (buf) * 32768 + 16384 + i * 8192 + tid * 16);            \
        }                                                                        \
    }

    f4 acc[2][4] = {};
    GSTAGE(0, 0);
    __syncthreads();
    int cur = 0;

    for (int k0 = 0; k0 < K; k0 += 64) {
        if (k0 + 64 < K) GSTAGE(cur ^ 1, k0 + 64);
        const char* Ab = L + cur * 32768;
        const char* Bb = Ab + 16384;
        bf8 af[2][2], bfr[2][4];
#pragma unroll
        for (int kk = 0; kk < 2; ++kk) {
            const int ch = ((kk * 4 + lhi) ^ (l15 & 7)) * 16;
#pragma unroll
            for (int m = 0; m < 2; ++m)
                af[kk][m] = *(const bf8*)(Ab + (wr * 32 + m * 16 + l15) * 128 + ch);
#pragma unroll
            for (int n = 0; n < 4; ++n)
                bfr[kk][n] = *(const bf8*)(Bb + (n * 32 + wc * 16 + l15) * 128 + ch);
        }
        __builtin_amdgcn_s_setprio(1);
#pragma unroll
        for (int kk = 0; kk < 2; ++kk)
#pragma unroll
            for (int m = 0; m < 2; ++m)
#pragma unroll
                for (int n = 0; n < 4; ++n)
                    acc[m][n] = mfma16(af[kk][m], bfr[kk][n], acc[m][n]);
        __builtin_amdgcn_s_setprio(0);
        __syncthreads();
        cur ^= 1;
    }
#undef GSTAGE

    const int row0 = blockIdx.y * 128 + wr * 32;
    if (MODE == 0) {
#pragma unroll
        for (int m = 0; m < 2; ++m)
#pragma unroll
            for (int n = 0; n < 4; ++n) {
                const int c = blockIdx.x * 128 + n * 32 + wc * 16 + l15;
#pragma unroll
                for (int j = 0; j < 4; ++j)
                    C[(size_t)(row0 + m * 16 + lhi * 4 + j) * N + c] = acc[m][n][j];
            }
    } else {
        const int bx = blockIdx.x;
        if (bx < 20) {
            // RoPE on fp32 acc: pair (n, n+2) = (d, d+64), d = n*32+wc*16+l15
            __bf16* dst0 = (bx < 16) ? (Qo + (size_t)bx * T_SEQ * DHEAD)
                                     : (Ko + (size_t)(bx - 16) * T_SEQ * DHEAD);
#pragma unroll
            for (int m = 0; m < 2; ++m)
#pragma unroll
                for (int n = 0; n < 2; ++n) {
                    const int d = n * 32 + wc * 16 + l15;
#pragma unroll
                    for (int j = 0; j < 4; ++j) {
                        const int t = row0 + m * 16 + lhi * 4 + j;
                        const float2 cs = tab[t * 64 + d];
                        const float a = acc[m][n][j], b = acc[m][n + 2][j];
                        dst0[(size_t)t * DHEAD + d]      = (__bf16)(a * cs.x - b * cs.y);
                        dst0[(size_t)t * DHEAD + d + 64] = (__bf16)(b * cs.x + a * cs.y);
                    }
                }
        } else {
            // V: write transposed VT[kvh][d][t], 4 consecutive t per lane
            __bf16* vdst = Vo + (size_t)(bx - 20) * DHEAD * T_SEQ;
#pragma unroll
            for (int m = 0; m < 2; ++m)
#pragma unroll
                for (int n = 0; n < 4; ++n) {
                    const int c = n * 32 + wc * 16 + l15;
                    bf4 o;
#pragma unroll
                    for (int j = 0; j < 4; ++j) o[j] = (__bf16)acc[m][n][j];
                    *(bf4*)&vdst[(size_t)c * T_SEQ + row0 + m * 16 + lhi * 4] = o;
                }
        }
    }
}

// ---------------- dual-softmax flash attention, key-split across wave halves ----------------
// grid (32,16) x 512 thr (8 waves). Waves 0-3: even key tiles; 4-7: odd key tiles,
// same 64 q-rows. Per-half online softmax; exact merge at end. K/V double-buffered
// 128-key rounds via global_load_lds (pre-swizzled source).
__global__ __launch_bounds__(512) void k_attn(const __bf16* __restrict__ Q,
                                              const __bf16* __restrict__ Kr,
                                              const __bf16* __restrict__ VT,
                                              __bf16* __restrict__ att) {
    __shared__ __align__(16) char lds[155648];
    char* KlB  = lds;               // [2][128 keys][256B d], 4-bit row XOR swz
    char* VlB  = lds + 65536;       // [2][128 d][256B keys], 4-bit row XOR swz
    char* PlB0 = lds + 131072;      // 8 waves x 2KB
    char* PwB0 = lds + 147456;      // 4 qw x 2KB (parity-active waves only)

    const int h = blockIdx.y, kvh = h >> 2;
    const int qt = (blockIdx.y < 8) ? (31 - (int)blockIdx.x) : (int)blockIdx.x;
    const int tid = threadIdx.x, wid = tid >> 6, lane = tid & 63;
    const int l15 = lane & 15, lhi = lane >> 4;
    const int par = wid >> 2, qw = wid & 3;
    const int q0w = qt * 64 + qw * 16;
    const bool hasloc = qt >= 4;
    const int lfLo = 4 * (qt >> 2) - 2;
    const int lpart = qt - 2;
    const float CE = 0.12751741f;                // (1/sqrt(128)) * log2(e)
    const float L2E = 1.44269504f;
    const float SCL = 0.08838834764831845f;
    const float THR = 5.5451774f;                // 8*ln2

    char* PlB = PlB0 + wid * 2048;
    char* PwB = PwB0 + qw * 2048;

    const int srow = tid >> 4;                        // 0..31
    const int sg = (((tid & 15) ^ (srow & 15)) << 3); // elem offset
    const __bf16* KgB = Kr + (size_t)kvh * T_SEQ * DHEAD;
    const __bf16* VgB = VT + (size_t)kvh * DHEAD * T_SEQ;

#define STAGE(bsel, kb2)                                                          \
    {                                                                             \
        _Pragma("unroll") for (int i = 0; i < 4; ++i) {                           \
            GLOAD16(KgB + (size_t)((kb2) + i * 32 + srow) * DHEAD + sg,           \
                    KlB + (bsel) + i * 8192 + tid * 16);                          \
            GLOAD16(VgB + (size_t)(i * 32 + srow) * T_SEQ + (kb2) + sg,           \
                    VlB + (bsel) + i * 8192 + tid * 16);                          \
        }                                                                         \
    }

    bf8 qf[4];
#pragma unroll
    for (int dc = 0; dc < 4; ++dc)
        qf[dc] = *(const bf8*)&Q[((size_t)h * T_SEQ + q0w + l15) * DHEAD + dc * 32 + lhi * 8];

    f4 oc[8] = {}, ow[8] = {};
    float mg[4], sgp[4], slp[4];
#pragma unroll
    for (int j = 0; j < 4; ++j) { mg[j] = -__builtin_inff(); sgp[j] = slp[j] = 0.f; }
    float mgmin = -__builtin_inff();

    const int R = (qt >> 1) + 1;
    STAGE(0, 0);
    __syncthreads();
    int cur = 0;

    for (int r = 0; r < R; ++r) {
        if (r + 1 < R) STAGE((cur ^ 1) * 32768, (r + 1) * 128);
        const int kt = 2 * r + par;
        if (kt <= qt) {
            const int kb = kt * 64;
            const int cb = cur * 32768;
            const int rowb = par * 64;
            // ---- QK^T ----
            f4 sc[4] = {};
            __builtin_amdgcn_s_setprio(1);
#pragma unroll
            for (int ks = 0; ks < 4; ++ks)
#pragma unroll
                for (int dc = 0; dc < 4; ++dc) {
                    bf8 kf = *(const bf8*)(KlB + cb + (rowb + ks * 16 + l15) * 256 +
                                           (((dc * 4 + lhi) ^ l15) << 4));
                    sc[ks] = mfma16(qf[dc], kf, sc[ks]);
                }
            __builtin_amdgcn_s_setprio(0);

            float t[4][4];
#pragma unroll
            for (int ks = 0; ks < 4; ++ks)
#pragma unroll
                for (int j = 0; j < 4; ++j) t[ks][j] = sc[ks][j];
            if (kt == qt) {  // causal mask (last tile only)
#pragma unroll
                for (int ks = 0; ks < 4; ++ks)
#pragma unroll
                    for (int j = 0; j < 4; ++j)
                        if (kb + ks * 16 + l15 > q0w + lhi * 4 + j) t[ks][j] = -3.0e38f;
            }
            // ---- single defer-max gate ----
            float mx = t[0][0];
#pragma unroll
            for (int ks = 0; ks < 4; ++ks)
#pragma unroll
                for (int j = 0; j < 4; ++j) mx = fmaxf(mx, t[ks][j]);
            mx *= SCL;
            if (!__all(mx <= mgmin + THR)) {
#pragma unroll
                for (int j = 0; j < 4; ++j) {
                    float m2 = fmaxf(fmaxf(t[0][j], t[1][j]), fmaxf(t[2][j], t[3][j])) * SCL;
#pragma unroll
                    for (int x = 1; x < 16; x <<= 1) m2 = fmaxf(m2, __shfl_xor(m2, x));
                    float mn = fmaxf(mg[j], m2);
                    float f = __builtin_amdgcn_exp2f((mg[j] - mn) * L2E);
                    mg[j] = mn;
                    sgp[j] *= f; slp[j] *= f;
#pragma unroll
                    for (int nd = 0; nd < 8; ++nd) { oc[nd][j] *= f; ow[nd][j] *= f; }
                }
                mgmin = fminf(fminf(mg[0], mg[1]), fminf(mg[2], mg[3]));
            }
            // ---- branch-free exp ----
            float p[4][4], psum[4];
#pragma unroll
            for (int j = 0; j < 4; ++j) {
                const float bj = mg[j] * L2E;
#pragma unroll
                for (int ks = 0; ks < 4; ++ks)
                    p[ks][j] = __builtin_amdgcn_exp2f(t[ks][j] * CE - bj);
                psum[j] = (p[0][j] + p[1][j]) + (p[2][j] + p[3][j]);
                sgp[j] += psum[j];
            }
            // ---- P stores ----
            const bool part = hasloc && (kt == lpart);
            if (!part) {
#pragma unroll
                for (int j = 0; j < 4; ++j) {
                    const int rsw = ((lhi * 4 + j) & 7) << 4;
                    const int rb = (lhi * 4 + j) * 128;
#pragma unroll
                    for (int ks = 0; ks < 4; ++ks)
                        *(__bf16*)(PlB + rb + ((ks * 32 + 2 * l15) ^ rsw)) = (__bf16)p[ks][j];
                }
            } else {
                const int e = q0w + lhi * 4 - 128 - kb - l15;
#pragma unroll
                for (int j = 0; j < 4; ++j) {
                    const int rsw = ((lhi * 4 + j) & 7) << 4;
                    const int rb = (lhi * 4 + j) * 128;
                    float lsum = 0.f;
#pragma unroll
                    for (int ks = 0; ks < 4; ++ks) {
                        float l = (ks * 16 <= e + j) ? p[ks][j] : 0.f;
                        lsum += l;
                        *(__bf16*)(PwB + rb + ((ks * 32 + 2 * l15) ^ rsw)) = (__bf16)l;
                        *(__bf16*)(PlB + rb + ((ks * 32 + 2 * l15) ^ rsw)) = (__bf16)(p[ks][j] - l);
                    }
                    slp[j] += lsum;
                }
            }
            const bool inwin = hasloc && kt >= lfLo && kt < lpart;
            if (inwin) {
#pragma unroll
                for (int j = 0; j < 4; ++j) slp[j] += psum[j];
            }
            // ---- PV ----
            const int psw = (l15 & 7) << 4;
            bf8 pf0 = *(const bf8*)(PlB + l15 * 128 + ((lhi << 4) ^ psw));
            bf8 pf1 = *(const bf8*)(PlB + l15 * 128 + ((64 + (lhi << 4)) ^ psw));
            const int vg0 = ((par * 8 + lhi) ^ l15) << 4;
            const int vg1 = ((par * 8 + 4 + lhi) ^ l15) << 4;
            __builtin_amdgcn_s_setprio(1);
            if (part) {
                bf8 pw0 = *(const bf8*)(PwB + l15 * 128 + ((lhi << 4) ^ psw));
                bf8 pw1 = *(const bf8*)(PwB + l15 * 128 + ((64 + (lhi << 4)) ^ psw));
#pragma unroll
                for (int nd = 0; nd < 8; ++nd) {
                    bf8 v0 = *(const bf8*)(VlB + cb + (nd * 16 + l15) * 256 + vg0);
                    bf8 v1 = *(const bf8*)(VlB + cb + (nd * 16 + l15) * 256 + vg1);
                    oc[nd] = mfma16(pf0, v0, oc[nd]);
                    oc[nd] = mfma16(pf1, v1, oc[nd]);
                    ow[nd] = mfma16(pw0, v0, ow[nd]);
                    ow[nd] = mfma16(pw1, v1, ow[nd]);
                }
            } else if (inwin) {
#pragma unroll
                for (int nd = 0; nd < 8; ++nd) {
                    bf8 v0 = *(const bf8*)(VlB + cb + (nd * 16 + l15) * 256 + vg0);
                    bf8 v1 = *(const bf8*)(VlB + cb + (nd * 16 + l15) * 256 + vg1);
                    ow[nd] = mfma16(pf0, v0, ow[nd]);
                    ow[nd] = mfma16(pf1, v1, ow[nd]);
                }
            } else {
#pragma unroll
                for (int nd = 0; nd < 8; ++nd) {
                    bf8 v0 = *(const bf8*)(VlB + cb + (nd * 16 + l15) * 256 + vg0);
                    bf8 v1 = *(const bf8*)(VlB + cb + (nd * 16 + l15) * 256 + vg1);
                    oc[nd] = mfma16(pf0, v0, oc[nd]);
                    oc[nd] = mfma16(pf1, v1, oc[nd]);
                }
            }
            __builtin_amdgcn_s_setprio(0);
        }
        __syncthreads();   // drains staging (vmcnt 0) + frees cur buffer
        cur ^= 1;
    }

    // ---- split-softmax merge: waves 4-7 -> LDS, waves 0-3 combine ----
    if (par) {
        char* sb = lds + qw * 20480 + lane * 320;
#pragma unroll
        for (int nd = 0; nd < 8; ++nd) *(f4*)(sb + nd * 16) = oc[nd];
#pragma unroll
        for (int nd = 0; nd < 8; ++nd) *(f4*)(sb + 128 + nd * 16) = ow[nd];
        f4 a, b, c;
#pragma unroll
        for (int j = 0; j < 4; ++j) { a[j] = mg[j]; b[j] = sgp[j]; c[j] = slp[j]; }
        *(f4*)(sb + 256) = a; *(f4*)(sb + 272) = b; *(f4*)(sb + 288) = c;
    }
    __syncthreads();
    if (!par) {
        char* sb = lds + qw * 20480 + lane * 320;
        f4 mB = *(const f4*)(sb + 256);
        f4 sB = *(const f4*)(sb + 272);
        f4 lB = *(const f4*)(sb + 288);
        float fA[4], fB[4];
#pragma unroll
        for (int j = 0; j < 4; ++j) {
            float ms = fmaxf(mg[j], mB[j]);
            fA[j] = __builtin_amdgcn_exp2f((mg[j] - ms) * L2E);
            fB[j] = __builtin_amdgcn_exp2f((mB[j] - ms) * L2E);
            sgp[j] = sgp[j] * fA[j] + sB[j] * fB[j];
            slp[j] = slp[j] * fA[j] + lB[j] * fB[j];
        }
#pragma unroll
        for (int nd = 0; nd < 8; ++nd) {
            f4 ocB = *(const f4*)(sb + nd * 16);
            f4 owB = *(const f4*)(sb + 128 + nd * 16);
#pragma unroll
            for (int j = 0; j < 4; ++j) {
                oc[nd][j] = oc[nd][j] * fA[j] + ocB[j] * fB[j];
                ow[nd][j] = ow[nd][j] * fA[j] + owB[j] * fB[j];
            }
        }
#pragma unroll
        for (int j = 0; j < 4; ++j) {
#pragma unroll
            for (int x = 1; x < 16; x <<= 1) {
                sgp[j] += __shfl_xor(sgp[j], x);
                slp[j] += __shfl_xor(slp[j], x);
            }
        }
        float rg[4], rl[4];
#pragma unroll
        for (int j = 0; j < 4; ++j) {
            rg[j] = 1.f / sgp[j];
            rl[j] = hasloc ? 0.5f / slp[j] : 0.f;
        }
#pragma unroll
        for (int nd = 0; nd < 8; ++nd)
#pragma unroll
            for (int j = 0; j < 4; ++j) {
                int q = q0w + lhi * 4 + j;
                float go = oc[nd][j] + ow[nd][j];
                float v = hasloc ? (go * (0.5f * rg[j]) + ow[nd][j] * rl[j]) : go * rg[j];
                att[(size_t)q * CDIM + h * DHEAD + nd * 16 + l15] = (__bf16)v;
            }
    }
#undef STAGE
}

// ---------------- launcher ----------------
extern "C" void kernel_launch(void* const* d_in, const int* in_sizes, int n_in,
                              void* d_out, int out_size, void* d_ws, size_t ws_size,
                              hipStream_t stream) {
    const float* x  = (const float*)d_in[0];
    const float* wq = (const float*)d_in[1];
    const float* wk = (const float*)d_in[2];
    const float* wv = (const float*)d_in[3];
    const float* wo = (const float*)d_in[4];
    char* ws = (char*)d_ws;

    __bf16* xbf   = (__bf16*)(ws + 0);          // 8 MB
    __bf16* wqkvT = (__bf16*)(ws + 8388608);    // 12 MB  [3072][2048]
    __bf16* woT   = (__bf16*)(ws + 20971520);   // 8 MB   [2048][2048]
    __bf16* Q     = (__bf16*)(ws + 41943040);   // 8 MB   [16][2048][128]
    __bf16* K     = (__bf16*)(ws + 50331648);   // 2 MB   [4][2048][128]
    __bf16* VTb   = (__bf16*)(ws + 52428800);   // 2 MB   [4][128][2048]
    __bf16* att   = (__bf16*)(ws + 54525952);   // 8 MB   [2048][2048]
    float*  tab   = (float*)(ws + 62914560);    // 1 MB   [2048][64][2]

    k_pre<<<14848, 256, 0, stream>>>(x, wq, wk, wv, wo, xbf, tab, wqkvT, woT);
    k_gemm<1><<<dim3(24, 16), 512, 0, stream>>>(xbf, wqkvT, nullptr, (const float2*)tab,
                                                Q, K, VTb, 2048, 3072, 2048);
    k_attn<<<dim3(32, 16), 512, 0, stream>>>(Q, K, VTb, att);
    k_gemm<0><<<dim3(16, 16), 512, 0, stream>>>(att, woT, (float*)d_out, nullptr,
                                                nullptr, nullptr, nullptr, 2048, 2048, 2048);
}